// Round 1
// baseline (2118.780 us; speedup 1.0000x reference)
//
#include <hip/hip_runtime.h>

// ColorGradientNet on MI355X — round 1: all-f32 vector kernels, correctness-first.
// Workspace layout (bytes):
//   idx  @ 0          : 32768*20 int32   = 2,621,440
//   x1   @ 2621440    : 32768*64  f32    = 8,388,608
//   x2   @ 11010048   : 32768*128 f32    = 16,777,216
//   x3   @ 27787264   : 32768*256 f32    = 33,554,432
//   x4p  @ 61341696   : 8*8*256   f32    = 65,536
//   xg   @ 61407232   : 8*1024    f32    = 32,768
//   w3f  @ 61440000   : 128*64    f32    = 32,768
//   h5   @ 61472768   : 32768*512 f32    = 67,108,864
//   h6   @ 128581632  : 32768*256 f32    = 33,554,432   (total ~154.6 MiB)

#define KNN 20
#define NPID 32768
#define RS 0.99999500003750f  // 1/sqrt(1+1e-5)

__device__ __forceinline__ float lrelu(float z) { return z >= 0.f ? z : 0.2f * z; }

// ---------------- kNN: one wave per point, iterative wave-argmax ----------------
// Distances replicate the reference formula exactly in f32 (no FMA contraction):
// pd = 2*(x.x'+y.y'+z.z') - xx_n - xx_m ; self-distance is exactly 0.
__global__ __launch_bounds__(256) void knn_kernel(const float* __restrict__ x, int* __restrict__ idxo) {
  const int lane = threadIdx.x & 63;
  const int pid = blockIdx.x * 4 + (threadIdx.x >> 6);
  const int b = pid >> 12, n = pid & 4095;
  const float* xb = x + (size_t)b * 40960;
  const float px = xb[n], py = xb[4096 + n], pz = xb[8192 + n];
  const float xxn = __fadd_rn(__fadd_rn(__fmul_rn(px, px), __fmul_rn(py, py)), __fmul_rn(pz, pz));
  float d[64];
  float lmax = -3.4e38f;
  int lm = lane;
#pragma unroll
  for (int j = 0; j < 64; ++j) {
    const int m = j * 64 + lane;
    const float qx = xb[m], qy = xb[4096 + m], qz = xb[8192 + m];
    const float xxm = __fadd_rn(__fadd_rn(__fmul_rn(qx, qx), __fmul_rn(qy, qy)), __fmul_rn(qz, qz));
    const float inner = __fadd_rn(__fadd_rn(__fmul_rn(px, qx), __fmul_rn(py, qy)), __fmul_rn(pz, qz));
    const float pd = __fsub_rn(__fsub_rn(__fmul_rn(2.0f, inner), xxn), xxm);
    d[j] = pd;
    if (pd > lmax) { lmax = pd; lm = m; }  // strict > keeps smallest index within lane
  }
  int* out = idxo + (size_t)pid * KNN;
#pragma unroll 1
  for (int it = 0; it < KNN; ++it) {
    float v = lmax;
    int mi = lm;
#pragma unroll
    for (int s = 1; s < 64; s <<= 1) {  // wave argmax, ties -> smaller index
      const float ov = __shfl_xor(v, s, 64);
      const int om = __shfl_xor(mi, s, 64);
      if (ov > v || (ov == v && om < mi)) { v = ov; mi = om; }
    }
    if (lane == 0) out[it] = mi;
    if ((mi & 63) == lane) {  // owner lane removes the winner and rescans (static idx via full unroll)
      const int kj = mi >> 6;
      lmax = -3.4e38f; lm = lane;
#pragma unroll
      for (int j = 0; j < 64; ++j) {
        if (j == kj) d[j] = -3.4e38f;
        if (d[j] > lmax) { lmax = d[j]; lm = j * 64 + lane; }
      }
    }
  }
}

// ---------------- edge features + MLP1(9->64) + MLP2(64->64) + max over k ----------------
__global__ __launch_bounds__(256) void edge_kernel(const float* __restrict__ x, const int* __restrict__ idxi,
    const float* __restrict__ w1, const float* __restrict__ g1, const float* __restrict__ b1,
    const float* __restrict__ w2, const float* __restrict__ g2, const float* __restrict__ b2,
    float* __restrict__ x1o) {
  __shared__ float fl[4][KNN][12];
  __shared__ float h1l[4][KNN][64];
  const int tid = threadIdx.x, wave = tid >> 6, lane = tid & 63;
  const int pid = blockIdx.x * 4 + wave;
  const int b = pid >> 12, n = pid & 4095;
  const float* xb = x + (size_t)b * 40960;
  if (lane < KNN) {
    const float c0 = xb[n], c1 = xb[4096 + n], c2 = xb[8192 + n];
    const float c3 = xb[12288 + n], c4 = xb[16384 + n], c5 = xb[20480 + n];
    const int mi = idxi[(size_t)pid * KNN + lane];
    float* fr = fl[wave][lane];
    fr[0] = c0; fr[1] = c1; fr[2] = c2;                  // center xyz
    fr[3] = c3; fr[4] = c4; fr[5] = c5;                  // center rgb
    fr[6] = c3 - xb[12288 + mi];                         // center rgb - neighbor rgb
    fr[7] = c4 - xb[16384 + mi];
    fr[8] = c5 - xb[20480 + mi];
  }
  float w1r[9];
#pragma unroll
  for (int c = 0; c < 9; ++c) w1r[c] = w1[lane * 9 + c];
  const float s1 = g1[lane] * RS, t1 = b1[lane];
  __syncthreads();
#pragma unroll 1
  for (int kk = 0; kk < KNN; ++kk) {
    float acc = 0.f;
#pragma unroll
    for (int c = 0; c < 9; ++c) acc += fl[wave][kk][c] * w1r[c];
    h1l[wave][kk][lane] = lrelu(acc * s1 + t1);
  }
  float w2r[64];  // own W2 row in registers; h1 reads are LDS broadcasts (conflict-free)
#pragma unroll
  for (int c = 0; c < 64; c += 4) *(float4*)&w2r[c] = *(const float4*)(w2 + lane * 64 + c);
  const float s2 = g2[lane] * RS, t2 = b2[lane];
  __syncthreads();
  float xmax = -3.4e38f;
#pragma unroll 1
  for (int kk = 0; kk < KNN; ++kk) {
    float acc = 0.f;
#pragma unroll
    for (int c = 0; c < 64; c += 4) {
      const float4 h = *(const float4*)&h1l[wave][kk][c];
      acc += h.x * w2r[c] + h.y * w2r[c + 1] + h.z * w2r[c + 2] + h.w * w2r[c + 3];
    }
    xmax = fmaxf(xmax, lrelu(acc * s2 + t2));
  }
  x1o[(size_t)pid * 64 + lane] = xmax;
}

// ---------------- generic f32 GEMM: out[m][o] = epi( dot(A[m,:], W[o,:]) ) ----------------
// 64x64 tile, Kchunk=32, XOR-swizzled LDS columns. MODE 1 gathers the l1 concat input
// [xg(1024,bcast over n) | x3(256) | x2(128) | x1(64)].
__device__ __forceinline__ int swz4(int row, int col4) { return col4 ^ (((row >> 2) & 7) << 2); }

template <int MODE>
__global__ __launch_bounds__(256) void gemm_kernel(
    const float* __restrict__ A, const float* __restrict__ W, float* __restrict__ out,
    const int Ktot, const int Nout, const int n_tiles,
    const float* __restrict__ gg, const float* __restrict__ bb,
    const float* __restrict__ linb, const int do_lrelu,
    const float* __restrict__ xg, const float* __restrict__ x3,
    const float* __restrict__ x2, const float* __restrict__ x1) {
  __shared__ float Al[64][32];
  __shared__ float Bl[64][32];
  const int nwg = gridDim.x;       // multiple of 8
  int id = blockIdx.x;
  id = (id & 7) * (nwg >> 3) + (id >> 3);  // bijective XCD swizzle; n-tile fast within chunk
  const int mt = id / n_tiles, nt = id - mt * n_tiles;
  const int m0 = mt * 64, o0 = nt * 64;
  const int tid = threadIdx.x;
  const int tx = tid & 15, ty = tid >> 4;
  float acc[4][4] = {};
  for (int kc = 0; kc < Ktot; kc += 32) {
#pragma unroll
    for (int r = 0; r < 2; ++r) {
      const int i = tid + r * 256;
      const int row = i >> 3, col4 = (i & 7) << 2;
      const int k = kc + col4;
      float4 va;
      if (MODE == 0) {
        va = *(const float4*)(A + (size_t)(m0 + row) * Ktot + k);
      } else {
        const int m = m0 + row;
        const float* src;
        if (k < 1024)      src = xg + ((m >> 12) << 10) + k;
        else if (k < 1280) src = x3 + (size_t)m * 256 + (k - 1024);
        else if (k < 1408) src = x2 + (size_t)m * 128 + (k - 1280);
        else               src = x1 + (size_t)m * 64  + (k - 1408);
        va = *(const float4*)src;
      }
      *(float4*)&Al[row][swz4(row, col4)] = va;
      const float4 vb = *(const float4*)(W + (size_t)(o0 + row) * Ktot + k);
      *(float4*)&Bl[row][swz4(row, col4)] = vb;
    }
    __syncthreads();
#pragma unroll
    for (int k = 0; k < 32; k += 4) {
      float4 a4[4], b4[4];
#pragma unroll
      for (int i = 0; i < 4; ++i) a4[i] = *(const float4*)&Al[ty * 4 + i][swz4(ty * 4 + i, k)];
#pragma unroll
      for (int j = 0; j < 4; ++j) b4[j] = *(const float4*)&Bl[tx * 4 + j][swz4(tx * 4 + j, k)];
#pragma unroll
      for (int i = 0; i < 4; ++i)
#pragma unroll
        for (int j = 0; j < 4; ++j)
          acc[i][j] += a4[i].x * b4[j].x + a4[i].y * b4[j].y + a4[i].z * b4[j].z + a4[i].w * b4[j].w;
    }
    __syncthreads();
  }
  float s[4], t[4];
#pragma unroll
  for (int j = 0; j < 4; ++j) {
    const int o = o0 + tx * 4 + j;
    s[j] = gg[o] * RS;
    t[j] = bb[o] + (linb ? linb[o] * s[j] : 0.f);  // bn(z + lin_b) = z*s + (lin_b*s + bn_b)
  }
#pragma unroll
  for (int i = 0; i < 4; ++i) {
    float4 v; float z;
    z = acc[i][0] * s[0] + t[0]; v.x = do_lrelu ? lrelu(z) : z;
    z = acc[i][1] * s[1] + t[1]; v.y = do_lrelu ? lrelu(z) : z;
    z = acc[i][2] * s[2] + t[2]; v.z = do_lrelu ? lrelu(z) : z;
    z = acc[i][3] * s[3] + t[3]; v.w = do_lrelu ? lrelu(z) : z;
    *(float4*)(out + (size_t)(m0 + ty * 4 + i) * Nout + o0 + tx * 4) = v;
  }
}

// ---------------- max over N (partial, 8 segments) ----------------
__global__ __launch_bounds__(256) void max_kernel(const float* __restrict__ x3, float* __restrict__ x4p) {
  __shared__ float red[4][64];
  const int bid = blockIdx.x;                       // 8b * 8seg * 4q
  const int q = bid & 3, seg = (bid >> 2) & 7, b = bid >> 5;
  const int cl = threadIdx.x & 63, nl = threadIdx.x >> 6;
  const int c = (q << 6) + cl;
  float acc = -3.4e38f;
  const int n0 = seg * 512;
  for (int n = n0 + nl; n < n0 + 512; n += 4)
    acc = fmaxf(acc, x3[((size_t)b * 4096 + n) * 256 + c]);
  red[nl][cl] = acc;
  __syncthreads();
  if (threadIdx.x < 64) {
    const float v = fmaxf(fmaxf(red[0][cl], red[1][cl]), fmaxf(red[2][cl], red[3][cl]));
    x4p[((size_t)b * 8 + seg) * 256 + c] = v;
  }
}

// ---------------- xg = lrelu(bn(x4 @ w5^T)) , one wave per output row ----------------
__global__ __launch_bounds__(256) void xg_kernel(const float* __restrict__ x4p, const float* __restrict__ w5,
    const float* __restrict__ g5, const float* __restrict__ b5, float* __restrict__ xg) {
  __shared__ float x4l[256];
  const int b = blockIdx.x, tid = threadIdx.x;
  float v = x4p[(size_t)b * 2048 + tid];
#pragma unroll
  for (int s2 = 1; s2 < 8; ++s2) v = fmaxf(v, x4p[(size_t)b * 2048 + s2 * 256 + tid]);
  x4l[tid] = v;
  __syncthreads();
  const int lane = tid & 63, wave = tid >> 6;
  const float4 xv = *(const float4*)&x4l[lane * 4];
#pragma unroll 1
  for (int o = wave; o < 1024; o += 4) {
    const float4 w = *(const float4*)(w5 + (size_t)o * 256 + lane * 4);
    float acc = xv.x * w.x + xv.y * w.y + xv.z * w.z + xv.w * w.w;
#pragma unroll
    for (int s = 1; s < 64; s <<= 1) acc += __shfl_xor(acc, s, 64);
    if (lane == 0) xg[(size_t)b * 1024 + o] = lrelu(acc * (g5[o] * RS) + b5[o]);
  }
}

// ---------------- final 256->2 + transpose to (B,2,N) ----------------
__global__ __launch_bounds__(256) void l3_kernel(const float* __restrict__ h6, const float* __restrict__ l3w,
    const float* __restrict__ l3b, float* __restrict__ out) {
  __shared__ float wl[512];
  const int tid = threadIdx.x;
  wl[tid] = l3w[tid]; wl[256 + tid] = l3w[256 + tid];
  __syncthreads();
  const int m = blockIdx.x * 256 + tid;
  float a0 = 0.f, a1 = 0.f;
#pragma unroll
  for (int c = 0; c < 256; c += 4) {
    const float4 h = *(const float4*)(h6 + (size_t)m * 256 + c);
    a0 += h.x * wl[c] + h.y * wl[c + 1] + h.z * wl[c + 2] + h.w * wl[c + 3];
    a1 += h.x * wl[256 + c] + h.y * wl[256 + c + 1] + h.z * wl[256 + c + 2] + h.w * wl[256 + c + 3];
  }
  const int b = m >> 12, n = m & 4095;
  out[(size_t)b * 8192 + n] = a0 + l3b[0];
  out[(size_t)b * 8192 + 4096 + n] = a1 + l3b[1];
}

// ---------------- w3 fold: input to x2 layer is concat([x1,x1]) ----------------
__global__ __launch_bounds__(256) void w3fold_kernel(const float* __restrict__ w3, float* __restrict__ w3f) {
  const int i = blockIdx.x * 256 + threadIdx.x;  // 8192
  const int o = i >> 6, c = i & 63;
  w3f[i] = w3[o * 128 + c] + w3[o * 128 + 64 + c];
}

extern "C" void kernel_launch(void* const* d_in, const int* in_sizes, int n_in,
                              void* d_out, int out_size, void* d_ws, size_t ws_size,
                              hipStream_t stream) {
  const float* x   = (const float*)d_in[0];
  const float* w1  = (const float*)d_in[2];
  const float* g1  = (const float*)d_in[3];
  const float* b1  = (const float*)d_in[4];
  const float* w2  = (const float*)d_in[5];
  const float* g2  = (const float*)d_in[6];
  const float* b2  = (const float*)d_in[7];
  const float* w3  = (const float*)d_in[8];
  const float* g3  = (const float*)d_in[9];
  const float* b3  = (const float*)d_in[10];
  const float* w4  = (const float*)d_in[11];
  const float* g4  = (const float*)d_in[12];
  const float* b4  = (const float*)d_in[13];
  const float* w5  = (const float*)d_in[14];
  const float* g5  = (const float*)d_in[15];
  const float* b5  = (const float*)d_in[16];
  const float* l1w = (const float*)d_in[17];
  const float* l1b = (const float*)d_in[18];
  const float* g6  = (const float*)d_in[19];
  const float* b6  = (const float*)d_in[20];
  const float* l2w = (const float*)d_in[21];
  const float* l2b = (const float*)d_in[22];
  const float* g7  = (const float*)d_in[23];
  const float* b7  = (const float*)d_in[24];
  const float* l3w = (const float*)d_in[25];
  const float* l3b = (const float*)d_in[26];
  float* outp = (float*)d_out;

  char* ws = (char*)d_ws;
  int*   idx = (int*)(ws + 0);
  float* x1  = (float*)(ws + 2621440);
  float* x2  = (float*)(ws + 11010048);
  float* x3  = (float*)(ws + 27787264);
  float* x4p = (float*)(ws + 61341696);
  float* xg  = (float*)(ws + 61407232);
  float* w3f = (float*)(ws + 61440000);
  float* h5  = (float*)(ws + 61472768);
  float* h6  = (float*)(ws + 128581632);

  knn_kernel<<<NPID / 4, 256, 0, stream>>>(x, idx);
  w3fold_kernel<<<32, 256, 0, stream>>>(w3, w3f);
  edge_kernel<<<NPID / 4, 256, 0, stream>>>(x, idx, w1, g1, b1, w2, g2, b2, x1);
  gemm_kernel<0><<<512 * 2, 256, 0, stream>>>(x1, w3f, x2, 64, 128, 2, g3, b3, nullptr, 1,
                                              nullptr, nullptr, nullptr, nullptr);
  gemm_kernel<0><<<512 * 4, 256, 0, stream>>>(x2, w4, x3, 128, 256, 4, g4, b4, nullptr, 1,
                                              nullptr, nullptr, nullptr, nullptr);
  max_kernel<<<256, 256, 0, stream>>>(x3, x4p);
  xg_kernel<<<8, 256, 0, stream>>>(x4p, w5, g5, b5, xg);
  gemm_kernel<1><<<512 * 8, 256, 0, stream>>>(nullptr, l1w, h5, 1472, 512, 8, g6, b6, l1b, 1,
                                              xg, x3, x2, x1);
  gemm_kernel<0><<<512 * 4, 256, 0, stream>>>(h5, l2w, h6, 512, 256, 4, g7, b7, l2b, 1,
                                              nullptr, nullptr, nullptr, nullptr);
  l3_kernel<<<128, 256, 0, stream>>>(h6, l3w, l3b, outp);
}

// Round 2
// 1249.755 us; speedup vs baseline: 1.6954x; 1.6954x over previous
//
#include <hip/hip_runtime.h>

// ColorGradientNet on MI355X — round 2: split-bf16 MFMA GEMMs (hi/lo, 3-MFMA ~f32 accuracy).
// Activations stored as bf16 plane pairs (hi plane, lo plane) — same bytes as f32.
// Workspace layout (bytes):
//   idx  @ 0          : 32768*20 int32                  = 2,621,440
//   x1   @ 2621440    : 2 planes x 2,097,152 ushort     = 8,388,608
//   x2   @ 11010048   : 2 x 4,194,304 ushort            = 16,777,216
//   x3   @ 27787264   : 2 x 8,388,608 ushort            = 33,554,432
//   x4p  @ 61341696   : 8*8*256 f32                     = 65,536
//   xg   @ 61407232   : 2 x 8,192 ushort                = 32,768
//   w3f  @ 61440000   : 2 x 8,192 ushort                = 32,768
//   w4p  @ 61472768   : 2 x 32,768 ushort               = 131,072
//   l2wp @ 61603840   : 2 x 131,072 ushort              = 524,288
//   l1wp @ 62128128   : 2 x 753,664 ushort              = 3,014,656
//   h5   @ 65142784   : 2 x 16,777,216 ushort           = 67,108,864  (end 132,251,648)
//   h6   @ 11010048   : 32768*256 f32 (overlays x2/x3 — dead after l1 gemm)

#define KNN 20
#define NPID 32768
#define RS 0.99999500003750f  // 1/sqrt(1+1e-5)

// concat-source plane offsets (elements)
#define XG_PO 8192
#define X3_PO 8388608
#define X2_PO 4194304
#define X1_PO 2097152

typedef unsigned short ushort_t;
typedef __attribute__((ext_vector_type(8))) short bf16x8;
typedef __attribute__((ext_vector_type(4))) float f32x4;

#define LDS_PTR(p) ((__attribute__((address_space(3))) void*)(p))
#define GLB_PTR(p) ((const __attribute__((address_space(1))) void*)(p))

__device__ __forceinline__ float lrelu(float z) { return z >= 0.f ? z : 0.2f * z; }
__device__ __forceinline__ unsigned short f2bf(float f) {
  unsigned int u = __float_as_uint(f);
  return (unsigned short)((u + 0x7fffu + ((u >> 16) & 1u)) >> 16);
}
__device__ __forceinline__ float bf2f(unsigned short h) { return __uint_as_float((unsigned int)h << 16); }

// ---------------- kNN: one wave per point, iterative wave-argmax ----------------
__global__ __launch_bounds__(256) void knn_kernel(const float* __restrict__ x, int* __restrict__ idxo) {
  const int lane = threadIdx.x & 63;
  const int pid = blockIdx.x * 4 + (threadIdx.x >> 6);
  const int b = pid >> 12, n = pid & 4095;
  const float* xb = x + (size_t)b * 40960;
  const float px = xb[n], py = xb[4096 + n], pz = xb[8192 + n];
  const float xxn = __fadd_rn(__fadd_rn(__fmul_rn(px, px), __fmul_rn(py, py)), __fmul_rn(pz, pz));
  float d[64];
  float lmax = -3.4e38f;
  int lm = lane;
#pragma unroll
  for (int j = 0; j < 64; ++j) {
    const int m = j * 64 + lane;
    const float qx = xb[m], qy = xb[4096 + m], qz = xb[8192 + m];
    const float xxm = __fadd_rn(__fadd_rn(__fmul_rn(qx, qx), __fmul_rn(qy, qy)), __fmul_rn(qz, qz));
    const float inner = __fadd_rn(__fadd_rn(__fmul_rn(px, qx), __fmul_rn(py, qy)), __fmul_rn(pz, qz));
    const float pd = __fsub_rn(__fsub_rn(__fmul_rn(2.0f, inner), xxn), xxm);
    d[j] = pd;
    if (pd > lmax) { lmax = pd; lm = m; }
  }
  int* out = idxo + (size_t)pid * KNN;
#pragma unroll 1
  for (int it = 0; it < KNN; ++it) {
    float v = lmax;
    int mi = lm;
#pragma unroll
    for (int s = 1; s < 64; s <<= 1) {
      const float ov = __shfl_xor(v, s, 64);
      const int om = __shfl_xor(mi, s, 64);
      if (ov > v || (ov == v && om < mi)) { v = ov; mi = om; }
    }
    if (lane == 0) out[it] = mi;
    if ((mi & 63) == lane) {
      const int kj = mi >> 6;
      lmax = -3.4e38f; lm = lane;
#pragma unroll
      for (int j = 0; j < 64; ++j) {
        if (j == kj) d[j] = -3.4e38f;
        if (d[j] > lmax) { lmax = d[j]; lm = j * 64 + lane; }
      }
    }
  }
}

// ---------------- edge features + MLP1(9->64) + MLP2(64->64) + max over k ----------------
__global__ __launch_bounds__(256) void edge_kernel(const float* __restrict__ x, const int* __restrict__ idxi,
    const float* __restrict__ w1, const float* __restrict__ g1, const float* __restrict__ b1,
    const float* __restrict__ w2, const float* __restrict__ g2, const float* __restrict__ b2,
    ushort_t* __restrict__ x1o) {
  __shared__ float fl[4][KNN][12];
  __shared__ float h1l[4][KNN][64];
  const int tid = threadIdx.x, wave = tid >> 6, lane = tid & 63;
  const int pid = blockIdx.x * 4 + wave;
  const int b = pid >> 12, n = pid & 4095;
  const float* xb = x + (size_t)b * 40960;
  if (lane < KNN) {
    const float c0 = xb[n], c1 = xb[4096 + n], c2 = xb[8192 + n];
    const float c3 = xb[12288 + n], c4 = xb[16384 + n], c5 = xb[20480 + n];
    const int mi = idxi[(size_t)pid * KNN + lane];
    float* fr = fl[wave][lane];
    fr[0] = c0; fr[1] = c1; fr[2] = c2;
    fr[3] = c3; fr[4] = c4; fr[5] = c5;
    fr[6] = c3 - xb[12288 + mi];
    fr[7] = c4 - xb[16384 + mi];
    fr[8] = c5 - xb[20480 + mi];
  }
  float w1r[9];
#pragma unroll
  for (int c = 0; c < 9; ++c) w1r[c] = w1[lane * 9 + c];
  const float s1 = g1[lane] * RS, t1 = b1[lane];
  __syncthreads();
#pragma unroll 1
  for (int kk = 0; kk < KNN; ++kk) {
    float acc = 0.f;
#pragma unroll
    for (int c = 0; c < 9; ++c) acc += fl[wave][kk][c] * w1r[c];
    h1l[wave][kk][lane] = lrelu(acc * s1 + t1);
  }
  float w2r[64];
#pragma unroll
  for (int c = 0; c < 64; c += 4) *(float4*)&w2r[c] = *(const float4*)(w2 + lane * 64 + c);
  const float s2 = g2[lane] * RS, t2 = b2[lane];
  __syncthreads();
  float xmax = -3.4e38f;
#pragma unroll 1
  for (int kk = 0; kk < KNN; ++kk) {
    float acc = 0.f;
#pragma unroll
    for (int c = 0; c < 64; c += 4) {
      const float4 h = *(const float4*)&h1l[wave][kk][c];
      acc += h.x * w2r[c] + h.y * w2r[c + 1] + h.z * w2r[c + 2] + h.w * w2r[c + 3];
    }
    xmax = fmaxf(xmax, lrelu(acc * s2 + t2));
  }
  const unsigned short h = f2bf(xmax);
  x1o[(size_t)pid * 64 + lane] = h;
  x1o[X1_PO + (size_t)pid * 64 + lane] = f2bf(xmax - bf2f(h));
}

// ---------------- weight prep: fold w3 + split all weights to bf16 hi/lo ----------------
__global__ __launch_bounds__(256) void prep_kernel(const float* __restrict__ w3, const float* __restrict__ w4,
    const float* __restrict__ l1w, const float* __restrict__ l2w,
    ushort_t* __restrict__ w3fp, ushort_t* __restrict__ w4p,
    ushort_t* __restrict__ l1wp, ushort_t* __restrict__ l2wp) {
  const int i = blockIdx.x * 256 + threadIdx.x;  // 0 .. 925695
  float f; ushort_t* hp; int n, j;
  if (i < 8192) {            // w3 folded: concat([x1,x1]) input
    const int o = i >> 6, c = i & 63;
    f = w3[o * 128 + c] + w3[o * 128 + 64 + c];
    hp = w3fp; n = 8192; j = i;
  } else if (i < 8192 + 32768) {
    j = i - 8192; f = w4[j]; hp = w4p; n = 32768;
  } else if (i < 8192 + 32768 + 131072) {
    j = i - 8192 - 32768; f = l2w[j]; hp = l2wp; n = 131072;
  } else if (i < 8192 + 32768 + 131072 + 753664) {
    j = i - 8192 - 32768 - 131072; f = l1w[j]; hp = l1wp; n = 753664;
  } else return;
  const unsigned short h = f2bf(f);
  hp[j] = h;
  hp[n + j] = f2bf(f - bf2f(h));
}

// ---------------- split-bf16 MFMA GEMM: out[m][o] = epi( A[m,:] . W[o,:] ) ----------------
// 128x128 tile, BK=64, 4 waves (64x64 each). LDS planes Ah|Al|Bh|Bl, each [128][64] bf16,
// XOR slot-swizzle (slot ^= row&7), staged by global_load_lds w16 with pre-swizzled source.
// MODE 0: A = hi plane (+aPO lo). MODE 1: gather concat [xg(1024)|x3(256)|x2(128)|x1(64)].
// OUTF32 0: out = bf16 hi plane (+outPO lo). OUTF32 1: out = f32.
template <int MODE, int OUTF32>
__global__ __launch_bounds__(256) void gemm_bf16(
    const ushort_t* __restrict__ A, const ushort_t* __restrict__ W, void* __restrict__ outv,
    const int Ktot, const int Nout, const int n_tiles,
    const int aPO, const int wPO, const int outPO,
    const float* __restrict__ gg, const float* __restrict__ bb,
    const float* __restrict__ linb, const int do_lrelu,
    const ushort_t* __restrict__ xg, const ushort_t* __restrict__ x3,
    const ushort_t* __restrict__ x2, const ushort_t* __restrict__ x1) {
  __shared__ __align__(16) ushort_t lds[32768];  // 64 KiB: 4 planes x [128][64]
  const int tid = threadIdx.x, lane = tid & 63, wid = tid >> 6;
  const int nwg = gridDim.x;
  int id = (blockIdx.x & 7) * (nwg >> 3) + (blockIdx.x >> 3);  // bijective XCD swizzle
  const int mt = id / n_tiles, nt = id - mt * n_tiles;         // n-tile fast: A-panel L2 reuse
  const int m0 = mt * 128, o0 = nt * 128;
  const int fr = lane & 15, kg = lane >> 4;
  const int wr = wid >> 1, wc = wid & 1;
  // staging geometry: wave `wid` stages plane `wid`; chunk c covers rows c*8..c*8+7
  const int srow = lane >> 3, sslot = lane & 7;
  // frag row indices + per-row swizzle
  int rA[4], rB[4];
#pragma unroll
  for (int i = 0; i < 4; ++i) { rA[i] = wr * 64 + i * 16 + fr; rB[i] = wc * 64 + i * 16 + fr; }
  f32x4 acc[4][4] = {};
  const ushort_t* srcB = (wid == 2) ? W : W + wPO;               // planes 2,3
  const ushort_t* srcA0 = (MODE == 0) ? ((wid == 0) ? A : A + aPO) : nullptr;
  const int pl = (wid == 1);                                     // MODE 1 lo-plane flag

  for (int kc = 0; kc < Ktot; kc += 64) {
    // ---- stage 64 KiB via global_load_lds (pre-swizzled global source) ----
#pragma unroll
    for (int c = 0; c < 16; ++c) {
      const int row = c * 8 + srow;
      const int rslot = sslot ^ (row & 7);
      const int k = kc + rslot * 8;
      const ushort_t* q;
      if (wid >= 2) {
        q = srcB + (size_t)(o0 + row) * Ktot + k;
      } else if (MODE == 0) {
        q = srcA0 + (size_t)(m0 + row) * Ktot + k;
      } else {
        const int m = m0 + row;
        if (k < 1024)      q = xg + pl * XG_PO + ((m >> 12) << 10) + k;
        else if (k < 1280) q = x3 + pl * X3_PO + (size_t)m * 256 + (k - 1024);
        else if (k < 1408) q = x2 + pl * X2_PO + (size_t)m * 128 + (k - 1280);
        else               q = x1 + pl * X1_PO + (size_t)m * 64 + (k - 1408);
      }
      __builtin_amdgcn_global_load_lds(GLB_PTR(q), LDS_PTR(&lds[wid * 8192 + c * 512]), 16, 0, 0);
    }
    __syncthreads();
    // ---- compute: 2 k-substeps x 16 frags x 3 MFMA ----
#pragma unroll
    for (int k0 = 0; k0 < 64; k0 += 32) {
      const int ks = (k0 >> 3) + kg;
      bf16x8 ah[4], al[4], bh[4], bl[4];
#pragma unroll
      for (int i = 0; i < 4; ++i) {
        const int off = rA[i] * 64 + ((ks ^ (rA[i] & 7)) << 3);
        ah[i] = *(const bf16x8*)&lds[off];
        al[i] = *(const bf16x8*)&lds[8192 + off];
      }
#pragma unroll
      for (int j = 0; j < 4; ++j) {
        const int off = rB[j] * 64 + ((ks ^ (rB[j] & 7)) << 3);
        bh[j] = *(const bf16x8*)&lds[16384 + off];
        bl[j] = *(const bf16x8*)&lds[24576 + off];
      }
#pragma unroll
      for (int i = 0; i < 4; ++i)
#pragma unroll
        for (int j = 0; j < 4; ++j) {
          acc[i][j] = __builtin_amdgcn_mfma_f32_16x16x32_bf16(ah[i], bh[j], acc[i][j], 0, 0, 0);
          acc[i][j] = __builtin_amdgcn_mfma_f32_16x16x32_bf16(ah[i], bl[j], acc[i][j], 0, 0, 0);
          acc[i][j] = __builtin_amdgcn_mfma_f32_16x16x32_bf16(al[i], bh[j], acc[i][j], 0, 0, 0);
        }
    }
    __syncthreads();
  }
  // ---- epilogue: bn(+linb) + lrelu; C/D map: col=lane&15, row=(lane>>4)*4+reg ----
  float s[4], t[4];
#pragma unroll
  for (int j = 0; j < 4; ++j) {
    const int o = o0 + wc * 64 + j * 16 + fr;
    s[j] = gg[o] * RS;
    t[j] = bb[o] + (linb ? linb[o] * s[j] : 0.f);
  }
#pragma unroll
  for (int i = 0; i < 4; ++i) {
#pragma unroll
    for (int j = 0; j < 4; ++j) {
      const int col = o0 + wc * 64 + j * 16 + fr;
#pragma unroll
      for (int r = 0; r < 4; ++r) {
        const int row = m0 + wr * 64 + i * 16 + kg * 4 + r;
        float z = acc[i][j][r] * s[j] + t[j];
        if (do_lrelu) z = lrelu(z);
        if (OUTF32) {
          ((float*)outv)[(size_t)row * Nout + col] = z;
        } else {
          ushort_t* oh = (ushort_t*)outv;
          const unsigned short h = f2bf(z);
          oh[(size_t)row * Nout + col] = h;
          oh[outPO + (size_t)row * Nout + col] = f2bf(z - bf2f(h));
        }
      }
    }
  }
}

// ---------------- max over N (partial, 8 segments); x3 is bf16 hi/lo ----------------
__global__ __launch_bounds__(256) void max_kernel(const ushort_t* __restrict__ x3, float* __restrict__ x4p) {
  __shared__ float red[4][64];
  const int bid = blockIdx.x;  // 8b * 8seg * 4q
  const int q = bid & 3, seg = (bid >> 2) & 7, b = bid >> 5;
  const int cl = threadIdx.x & 63, nl = threadIdx.x >> 6;
  const int c = (q << 6) + cl;
  float acc = -3.4e38f;
  const int n0 = seg * 512;
  for (int n = n0 + nl; n < n0 + 512; n += 4) {
    const size_t e = ((size_t)b * 4096 + n) * 256 + c;
    acc = fmaxf(acc, bf2f(x3[e]) + bf2f(x3[X3_PO + e]));
  }
  red[nl][cl] = acc;
  __syncthreads();
  if (threadIdx.x < 64) {
    x4p[((size_t)b * 8 + seg) * 256 + c] = fmaxf(fmaxf(red[0][cl], red[1][cl]), fmaxf(red[2][cl], red[3][cl]));
  }
}

// ---------------- xg = lrelu(bn(x4 @ w5^T)) ----------------
__global__ __launch_bounds__(256) void xg_kernel(const float* __restrict__ x4p, const float* __restrict__ w5,
    const float* __restrict__ g5, const float* __restrict__ b5, ushort_t* __restrict__ xgo) {
  __shared__ float x4l[256];
  const int b = blockIdx.x, tid = threadIdx.x;
  float v = x4p[(size_t)b * 2048 + tid];
#pragma unroll
  for (int s2 = 1; s2 < 8; ++s2) v = fmaxf(v, x4p[(size_t)b * 2048 + s2 * 256 + tid]);
  x4l[tid] = v;
  __syncthreads();
  const int lane = tid & 63, wave = tid >> 6;
  const float4 xv = *(const float4*)&x4l[lane * 4];
#pragma unroll 1
  for (int o = wave; o < 1024; o += 4) {
    const float4 w = *(const float4*)(w5 + (size_t)o * 256 + lane * 4);
    float acc = xv.x * w.x + xv.y * w.y + xv.z * w.z + xv.w * w.w;
#pragma unroll
    for (int s = 1; s < 64; s <<= 1) acc += __shfl_xor(acc, s, 64);
    if (lane == 0) {
      const float z = lrelu(acc * (g5[o] * RS) + b5[o]);
      const unsigned short h = f2bf(z);
      xgo[(size_t)b * 1024 + o] = h;
      xgo[XG_PO + (size_t)b * 1024 + o] = f2bf(z - bf2f(h));
    }
  }
}

// ---------------- final 256->2 + transpose to (B,2,N) ----------------
__global__ __launch_bounds__(256) void l3_kernel(const float* __restrict__ h6, const float* __restrict__ l3w,
    const float* __restrict__ l3b, float* __restrict__ out) {
  __shared__ float wl[512];
  const int tid = threadIdx.x;
  wl[tid] = l3w[tid]; wl[256 + tid] = l3w[256 + tid];
  __syncthreads();
  const int m = blockIdx.x * 256 + tid;
  float a0 = 0.f, a1 = 0.f;
#pragma unroll
  for (int c = 0; c < 256; c += 4) {
    const float4 h = *(const float4*)(h6 + (size_t)m * 256 + c);
    a0 += h.x * wl[c] + h.y * wl[c + 1] + h.z * wl[c + 2] + h.w * wl[c + 3];
    a1 += h.x * wl[256 + c] + h.y * wl[256 + c + 1] + h.z * wl[256 + c + 2] + h.w * wl[256 + c + 3];
  }
  const int b = m >> 12, n = m & 4095;
  out[(size_t)b * 8192 + n] = a0 + l3b[0];
  out[(size_t)b * 8192 + 4096 + n] = a1 + l3b[1];
}

extern "C" void kernel_launch(void* const* d_in, const int* in_sizes, int n_in,
                              void* d_out, int out_size, void* d_ws, size_t ws_size,
                              hipStream_t stream) {
  const float* x   = (const float*)d_in[0];
  const float* w1  = (const float*)d_in[2];
  const float* g1  = (const float*)d_in[3];
  const float* b1  = (const float*)d_in[4];
  const float* w2  = (const float*)d_in[5];
  const float* g2  = (const float*)d_in[6];
  const float* b2  = (const float*)d_in[7];
  const float* w3  = (const float*)d_in[8];
  const float* g3  = (const float*)d_in[9];
  const float* b3  = (const float*)d_in[10];
  const float* w4  = (const float*)d_in[11];
  const float* g4  = (const float*)d_in[12];
  const float* b4  = (const float*)d_in[13];
  const float* w5  = (const float*)d_in[14];
  const float* g5  = (const float*)d_in[15];
  const float* b5  = (const float*)d_in[16];
  const float* l1w = (const float*)d_in[17];
  const float* l1b = (const float*)d_in[18];
  const float* g6  = (const float*)d_in[19];
  const float* b6  = (const float*)d_in[20];
  const float* l2w = (const float*)d_in[21];
  const float* l2b = (const float*)d_in[22];
  const float* g7  = (const float*)d_in[23];
  const float* b7  = (const float*)d_in[24];
  const float* l3w = (const float*)d_in[25];
  const float* l3b = (const float*)d_in[26];
  float* outp = (float*)d_out;

  char* ws = (char*)d_ws;
  int*      idx  = (int*)(ws + 0);
  ushort_t* x1   = (ushort_t*)(ws + 2621440);
  ushort_t* x2   = (ushort_t*)(ws + 11010048);
  ushort_t* x3   = (ushort_t*)(ws + 27787264);
  float*    x4p  = (float*)(ws + 61341696);
  ushort_t* xgp  = (ushort_t*)(ws + 61407232);
  ushort_t* w3fp = (ushort_t*)(ws + 61440000);
  ushort_t* w4p  = (ushort_t*)(ws + 61472768);
  ushort_t* l2wp = (ushort_t*)(ws + 61603840);
  ushort_t* l1wp = (ushort_t*)(ws + 62128128);
  ushort_t* h5   = (ushort_t*)(ws + 65142784);
  float*    h6   = (float*)(ws + 11010048);  // overlays x2/x3 (dead after l1 gemm)

  knn_kernel<<<NPID / 4, 256, 0, stream>>>(x, idx);
  prep_kernel<<<3617, 256, 0, stream>>>(w3, w4, l1w, l2w, w3fp, w4p, l1wp, l2wp);
  edge_kernel<<<NPID / 4, 256, 0, stream>>>(x, idx, w1, g1, b1, w2, g2, b2, x1);
  // x2 = lrelu(bn(x1 @ w3f^T))      M=32768 K=64  O=128
  gemm_bf16<0, 0><<<256, 256, 0, stream>>>(x1, w3fp, x2, 64, 128, 1, X1_PO, 8192, X2_PO,
                                           g3, b3, nullptr, 1, nullptr, nullptr, nullptr, nullptr);
  // x3 = lrelu(bn(x2 @ w4^T))       K=128 O=256
  gemm_bf16<0, 0><<<512, 256, 0, stream>>>(x2, w4p, x3, 128, 256, 2, X2_PO, 32768, X3_PO,
                                           g4, b4, nullptr, 1, nullptr, nullptr, nullptr, nullptr);
  max_kernel<<<256, 256, 0, stream>>>(x3, x4p);
  xg_kernel<<<8, 256, 0, stream>>>(x4p, w5, g5, b5, xgp);
  // h5 = lrelu(bn(feat @ l1w^T + l1b))  K=1472 O=512  (concat gather)
  gemm_bf16<1, 0><<<1024, 256, 0, stream>>>(nullptr, l1wp, h5, 1472, 512, 4, 0, 753664, 16777216,
                                            g6, b6, l1b, 1, xgp, x3, x2, x1);
  // h6 = lrelu(bn(h5 @ l2w^T + l2b))    K=512 O=256  -> f32
  gemm_bf16<0, 1><<<512, 256, 0, stream>>>(h5, l2wp, h6, 512, 256, 2, 16777216, 131072, 0,
                                           g7, b7, l2b, 1, nullptr, nullptr, nullptr, nullptr);
  l3_kernel<<<128, 256, 0, stream>>>(h6, l3w, l3b, outp);
}

// Round 3
// 929.880 us; speedup vs baseline: 2.2786x; 1.3440x over previous
//
#include <hip/hip_runtime.h>

// ColorGradientNet on MI355X — round 3: kNN selection via threshold + bitonic (3.3x fewer inst).
// GEMMs: split-bf16 MFMA (hi/lo, 3-MFMA ~f32 accuracy), unchanged from round 2.
// Workspace layout (bytes):
//   idx  @ 0          : 32768*20 int32                  = 2,621,440
//   x1   @ 2621440    : 2 planes x 2,097,152 ushort     = 8,388,608
//   x2   @ 11010048   : 2 x 4,194,304 ushort            = 16,777,216
//   x3   @ 27787264   : 2 x 8,388,608 ushort            = 33,554,432
//   x4p  @ 61341696   : 8*8*256 f32                     = 65,536
//   xg   @ 61407232   : 2 x 8,192 ushort                = 32,768
//   w3f  @ 61440000   : 2 x 8,192 ushort                = 32,768
//   w4p  @ 61472768   : 2 x 32,768 ushort               = 131,072
//   l2wp @ 61603840   : 2 x 131,072 ushort              = 524,288
//   l1wp @ 62128128   : 2 x 753,664 ushort              = 3,014,656
//   h5   @ 65142784   : 2 x 16,777,216 ushort           = 67,108,864  (end 132,251,648)
//   h6   @ 11010048   : 32768*256 f32 (overlays x2/x3 — dead after l1 gemm)

#define KNN 20
#define NPID 32768
#define RS 0.99999500003750f  // 1/sqrt(1+1e-5)

// concat-source plane offsets (elements)
#define XG_PO 8192
#define X3_PO 8388608
#define X2_PO 4194304
#define X1_PO 2097152

typedef unsigned short ushort_t;
typedef __attribute__((ext_vector_type(8))) short bf16x8;
typedef __attribute__((ext_vector_type(4))) float f32x4;

#define LDS_PTR(p) ((__attribute__((address_space(3))) void*)(p))
#define GLB_PTR(p) ((const __attribute__((address_space(1))) void*)(p))

__device__ __forceinline__ float lrelu(float z) { return z >= 0.f ? z : 0.2f * z; }
__device__ __forceinline__ unsigned short f2bf(float f) {
  unsigned int u = __float_as_uint(f);
  return (unsigned short)((u + 0x7fffu + ((u >> 16) & 1u)) >> 16);
}
__device__ __forceinline__ float bf2f(unsigned short h) { return __uint_as_float((unsigned int)h << 16); }

// ---------------- kNN: threshold from sorted lane-maxima + one bitonic sort ----------------
// Distances replicate the reference f32 op order exactly (no FMA contraction), so the
// selected neighbor SET matches numpy bit-for-bit (downstream max-over-k is set-invariant).
__global__ __launch_bounds__(256) void knn_kernel(const float* __restrict__ x, int* __restrict__ idxo) {
  __shared__ float cval[4][64];
  __shared__ int cidx[4][64];
  __shared__ int ccnt[4];
  const int lane = threadIdx.x & 63, wave = threadIdx.x >> 6;
  const int pid = blockIdx.x * 4 + wave;
  const int b = pid >> 12, n = pid & 4095;
  const float* xb = x + (size_t)b * 40960;
  const float px = xb[n], py = xb[4096 + n], pz = xb[8192 + n];
  const float xxn = __fadd_rn(__fadd_rn(__fmul_rn(px, px), __fmul_rn(py, py)), __fmul_rn(pz, pz));
  float d[64];
  float lmax = -3.4e38f;
#pragma unroll
  for (int j = 0; j < 64; ++j) {
    const int m = j * 64 + lane;
    const float qx = xb[m], qy = xb[4096 + m], qz = xb[8192 + m];
    const float xxm = __fadd_rn(__fadd_rn(__fmul_rn(qx, qx), __fmul_rn(qy, qy)), __fmul_rn(qz, qz));
    const float inner = __fadd_rn(__fadd_rn(__fmul_rn(px, qx), __fmul_rn(py, qy)), __fmul_rn(pz, qz));
    const float pd = __fsub_rn(__fsub_rn(__fmul_rn(2.0f, inner), xxn), xxm);
    d[j] = pd;
    lmax = fmaxf(lmax, pd);
  }
  if (threadIdx.x < 4) ccnt[threadIdx.x] = 0;
  __syncthreads();
  // bitonic sort of the 64 lane maxima, descending (value only)
  float v = lmax;
#pragma unroll
  for (int k = 2; k <= 64; k <<= 1) {
#pragma unroll
    for (int j = k >> 1; j > 0; j >>= 1) {
      const float ov = __shfl_xor(v, j, 64);
      const bool keepMax = (((lane & k) == 0) == ((lane & j) == 0));
      v = keepMax ? fmaxf(v, ov) : fminf(v, ov);
    }
  }
  const float t0 = __shfl(v, 19, 64);  // lower bound on true 20th-largest
  // collect candidates >= t0 (E[count] ~ 24, guaranteed >= 20)
#pragma unroll
  for (int j = 0; j < 64; ++j) {
    if (d[j] >= t0) {
      const int s = atomicAdd(&ccnt[wave], 1);
      if (s < 64) { cval[wave][s] = d[j]; cidx[wave][s] = j * 64 + lane; }
    }
  }
  __syncthreads();
  const int C = ccnt[wave];
  int* out = idxo + (size_t)pid * KNN;
  if (C <= 64) {
    // pack (value desc, index asc) into one u64 key; lanes >= C get key 0 (sorts last)
    unsigned long long key = 0ull;
    if (lane < C) {
      const unsigned int u = __float_as_uint(cval[wave][lane]);
      const unsigned int ou = (u & 0x80000000u) ? ~u : (u | 0x80000000u);
      key = ((unsigned long long)ou << 32) | (unsigned long long)(0xFFFFFFFFu - (unsigned int)cidx[wave][lane]);
    }
#pragma unroll
    for (int k = 2; k <= 64; k <<= 1) {
#pragma unroll
      for (int j = k >> 1; j > 0; j >>= 1) {
        const unsigned long long ok = (unsigned long long)__shfl_xor((long long)key, j, 64);
        const bool keepMax = (((lane & k) == 0) == ((lane & j) == 0));
        const bool gt = key > ok;
        key = (keepMax == gt) ? key : ok;
      }
    }
    if (lane < KNN) out[lane] = (int)(0xFFFFFFFFu - (unsigned int)key);
  } else {
    // exact fallback (statistically never taken): iterative wave-argmax with removal
    unsigned long long used = 0ull;
#pragma unroll 1
    for (int it = 0; it < KNN; ++it) {
      float lv = -3.4e38f;
      int li = 1 << 30;
#pragma unroll
      for (int j = 0; j < 64; ++j)
        if (!((used >> j) & 1ull) && d[j] > lv) { lv = d[j]; li = j * 64 + lane; }
      float bv = lv;
      int bi = li;
#pragma unroll
      for (int s = 1; s < 64; s <<= 1) {
        const float ovv = __shfl_xor(bv, s, 64);
        const int oii = __shfl_xor(bi, s, 64);
        if (ovv > bv || (ovv == bv && oii < bi)) { bv = ovv; bi = oii; }
      }
      if (lane == 0) out[it] = bi;
      if ((bi & 63) == lane) used |= 1ull << (bi >> 6);
    }
  }
}

// ---------------- edge features + MLP1(9->64) + MLP2(64->64) + max over k ----------------
__global__ __launch_bounds__(256) void edge_kernel(const float* __restrict__ x, const int* __restrict__ idxi,
    const float* __restrict__ w1, const float* __restrict__ g1, const float* __restrict__ b1,
    const float* __restrict__ w2, const float* __restrict__ g2, const float* __restrict__ b2,
    ushort_t* __restrict__ x1o) {
  __shared__ float fl[4][KNN][12];
  __shared__ float h1l[4][KNN][64];
  const int tid = threadIdx.x, wave = tid >> 6, lane = tid & 63;
  const int pid = blockIdx.x * 4 + wave;
  const int b = pid >> 12, n = pid & 4095;
  const float* xb = x + (size_t)b * 40960;
  if (lane < KNN) {
    const float c0 = xb[n], c1 = xb[4096 + n], c2 = xb[8192 + n];
    const float c3 = xb[12288 + n], c4 = xb[16384 + n], c5 = xb[20480 + n];
    const int mi = idxi[(size_t)pid * KNN + lane];
    float* fr = fl[wave][lane];
    fr[0] = c0; fr[1] = c1; fr[2] = c2;
    fr[3] = c3; fr[4] = c4; fr[5] = c5;
    fr[6] = c3 - xb[12288 + mi];
    fr[7] = c4 - xb[16384 + mi];
    fr[8] = c5 - xb[20480 + mi];
  }
  float w1r[9];
#pragma unroll
  for (int c = 0; c < 9; ++c) w1r[c] = w1[lane * 9 + c];
  const float s1 = g1[lane] * RS, t1 = b1[lane];
  __syncthreads();
#pragma unroll 1
  for (int kk = 0; kk < KNN; ++kk) {
    float acc = 0.f;
#pragma unroll
    for (int c = 0; c < 9; ++c) acc += fl[wave][kk][c] * w1r[c];
    h1l[wave][kk][lane] = lrelu(acc * s1 + t1);
  }
  float w2r[64];
#pragma unroll
  for (int c = 0; c < 64; c += 4) *(float4*)&w2r[c] = *(const float4*)(w2 + lane * 64 + c);
  const float s2 = g2[lane] * RS, t2 = b2[lane];
  __syncthreads();
  float xmax = -3.4e38f;
#pragma unroll 1
  for (int kk = 0; kk < KNN; ++kk) {
    float acc = 0.f;
#pragma unroll
    for (int c = 0; c < 64; c += 4) {
      const float4 h = *(const float4*)&h1l[wave][kk][c];
      acc += h.x * w2r[c] + h.y * w2r[c + 1] + h.z * w2r[c + 2] + h.w * w2r[c + 3];
    }
    xmax = fmaxf(xmax, lrelu(acc * s2 + t2));
  }
  const unsigned short h = f2bf(xmax);
  x1o[(size_t)pid * 64 + lane] = h;
  x1o[X1_PO + (size_t)pid * 64 + lane] = f2bf(xmax - bf2f(h));
}

// ---------------- weight prep: fold w3 + split all weights to bf16 hi/lo ----------------
__global__ __launch_bounds__(256) void prep_kernel(const float* __restrict__ w3, const float* __restrict__ w4,
    const float* __restrict__ l1w, const float* __restrict__ l2w,
    ushort_t* __restrict__ w3fp, ushort_t* __restrict__ w4p,
    ushort_t* __restrict__ l1wp, ushort_t* __restrict__ l2wp) {
  const int i = blockIdx.x * 256 + threadIdx.x;  // 0 .. 925695
  float f; ushort_t* hp; int n, j;
  if (i < 8192) {            // w3 folded: concat([x1,x1]) input
    const int o = i >> 6, c = i & 63;
    f = w3[o * 128 + c] + w3[o * 128 + 64 + c];
    hp = w3fp; n = 8192; j = i;
  } else if (i < 8192 + 32768) {
    j = i - 8192; f = w4[j]; hp = w4p; n = 32768;
  } else if (i < 8192 + 32768 + 131072) {
    j = i - 8192 - 32768; f = l2w[j]; hp = l2wp; n = 131072;
  } else if (i < 8192 + 32768 + 131072 + 753664) {
    j = i - 8192 - 32768 - 131072; f = l1w[j]; hp = l1wp; n = 753664;
  } else return;
  const unsigned short h = f2bf(f);
  hp[j] = h;
  hp[n + j] = f2bf(f - bf2f(h));
}

// ---------------- split-bf16 MFMA GEMM: out[m][o] = epi( A[m,:] . W[o,:] ) ----------------
// 128x128 tile, BK=64, 4 waves (64x64 each). LDS planes Ah|Al|Bh|Bl, each [128][64] bf16,
// XOR slot-swizzle (slot ^= row&7), staged by global_load_lds w16 with pre-swizzled source.
// MODE 0: A = hi plane (+aPO lo). MODE 1: gather concat [xg(1024)|x3(256)|x2(128)|x1(64)].
// OUTF32 0: out = bf16 hi plane (+outPO lo). OUTF32 1: out = f32.
template <int MODE, int OUTF32>
__global__ __launch_bounds__(256) void gemm_bf16(
    const ushort_t* __restrict__ A, const ushort_t* __restrict__ W, void* __restrict__ outv,
    const int Ktot, const int Nout, const int n_tiles,
    const int aPO, const int wPO, const int outPO,
    const float* __restrict__ gg, const float* __restrict__ bb,
    const float* __restrict__ linb, const int do_lrelu,
    const ushort_t* __restrict__ xg, const ushort_t* __restrict__ x3,
    const ushort_t* __restrict__ x2, const ushort_t* __restrict__ x1) {
  __shared__ __align__(16) ushort_t lds[32768];  // 64 KiB: 4 planes x [128][64]
  const int tid = threadIdx.x, lane = tid & 63, wid = tid >> 6;
  const int nwg = gridDim.x;
  int id = (blockIdx.x & 7) * (nwg >> 3) + (blockIdx.x >> 3);  // bijective XCD swizzle
  const int mt = id / n_tiles, nt = id - mt * n_tiles;         // n-tile fast: A-panel L2 reuse
  const int m0 = mt * 128, o0 = nt * 128;
  const int fr = lane & 15, kg = lane >> 4;
  const int wr = wid >> 1, wc = wid & 1;
  const int srow = lane >> 3, sslot = lane & 7;
  int rA[4], rB[4];
#pragma unroll
  for (int i = 0; i < 4; ++i) { rA[i] = wr * 64 + i * 16 + fr; rB[i] = wc * 64 + i * 16 + fr; }
  f32x4 acc[4][4] = {};
  const ushort_t* srcB = (wid == 2) ? W : W + wPO;               // planes 2,3
  const ushort_t* srcA0 = (MODE == 0) ? ((wid == 0) ? A : A + aPO) : nullptr;
  const int pl = (wid == 1);                                     // MODE 1 lo-plane flag

  for (int kc = 0; kc < Ktot; kc += 64) {
#pragma unroll
    for (int c = 0; c < 16; ++c) {
      const int row = c * 8 + srow;
      const int rslot = sslot ^ (row & 7);
      const int k = kc + rslot * 8;
      const ushort_t* q;
      if (wid >= 2) {
        q = srcB + (size_t)(o0 + row) * Ktot + k;
      } else if (MODE == 0) {
        q = srcA0 + (size_t)(m0 + row) * Ktot + k;
      } else {
        const int m = m0 + row;
        if (k < 1024)      q = xg + pl * XG_PO + ((m >> 12) << 10) + k;
        else if (k < 1280) q = x3 + pl * X3_PO + (size_t)m * 256 + (k - 1024);
        else if (k < 1408) q = x2 + pl * X2_PO + (size_t)m * 128 + (k - 1280);
        else               q = x1 + pl * X1_PO + (size_t)m * 64 + (k - 1408);
      }
      __builtin_amdgcn_global_load_lds(GLB_PTR(q), LDS_PTR(&lds[wid * 8192 + c * 512]), 16, 0, 0);
    }
    __syncthreads();
#pragma unroll
    for (int k0 = 0; k0 < 64; k0 += 32) {
      const int ks = (k0 >> 3) + kg;
      bf16x8 ah[4], al[4], bh[4], bl[4];
#pragma unroll
      for (int i = 0; i < 4; ++i) {
        const int off = rA[i] * 64 + ((ks ^ (rA[i] & 7)) << 3);
        ah[i] = *(const bf16x8*)&lds[off];
        al[i] = *(const bf16x8*)&lds[8192 + off];
      }
#pragma unroll
      for (int j = 0; j < 4; ++j) {
        const int off = rB[j] * 64 + ((ks ^ (rB[j] & 7)) << 3);
        bh[j] = *(const bf16x8*)&lds[16384 + off];
        bl[j] = *(const bf16x8*)&lds[24576 + off];
      }
#pragma unroll
      for (int i = 0; i < 4; ++i)
#pragma unroll
        for (int j = 0; j < 4; ++j) {
          acc[i][j] = __builtin_amdgcn_mfma_f32_16x16x32_bf16(ah[i], bh[j], acc[i][j], 0, 0, 0);
          acc[i][j] = __builtin_amdgcn_mfma_f32_16x16x32_bf16(ah[i], bl[j], acc[i][j], 0, 0, 0);
          acc[i][j] = __builtin_amdgcn_mfma_f32_16x16x32_bf16(al[i], bh[j], acc[i][j], 0, 0, 0);
        }
    }
    __syncthreads();
  }
  float s[4], t[4];
#pragma unroll
  for (int j = 0; j < 4; ++j) {
    const int o = o0 + wc * 64 + j * 16 + fr;
    s[j] = gg[o] * RS;
    t[j] = bb[o] + (linb ? linb[o] * s[j] : 0.f);
  }
#pragma unroll
  for (int i = 0; i < 4; ++i) {
#pragma unroll
    for (int j = 0; j < 4; ++j) {
      const int col = o0 + wc * 64 + j * 16 + fr;
#pragma unroll
      for (int r = 0; r < 4; ++r) {
        const int row = m0 + wr * 64 + i * 16 + kg * 4 + r;
        float z = acc[i][j][r] * s[j] + t[j];
        if (do_lrelu) z = lrelu(z);
        if (OUTF32) {
          ((float*)outv)[(size_t)row * Nout + col] = z;
        } else {
          ushort_t* oh = (ushort_t*)outv;
          const unsigned short h = f2bf(z);
          oh[(size_t)row * Nout + col] = h;
          oh[outPO + (size_t)row * Nout + col] = f2bf(z - bf2f(h));
        }
      }
    }
  }
}

// ---------------- max over N (partial, 8 segments); x3 is bf16 hi/lo ----------------
__global__ __launch_bounds__(256) void max_kernel(const ushort_t* __restrict__ x3, float* __restrict__ x4p) {
  __shared__ float red[4][64];
  const int bid = blockIdx.x;  // 8b * 8seg * 4q
  const int q = bid & 3, seg = (bid >> 2) & 7, b = bid >> 5;
  const int cl = threadIdx.x & 63, nl = threadIdx.x >> 6;
  const int c = (q << 6) + cl;
  float acc = -3.4e38f;
  const int n0 = seg * 512;
  for (int n = n0 + nl; n < n0 + 512; n += 4) {
    const size_t e = ((size_t)b * 4096 + n) * 256 + c;
    acc = fmaxf(acc, bf2f(x3[e]) + bf2f(x3[X3_PO + e]));
  }
  red[nl][cl] = acc;
  __syncthreads();
  if (threadIdx.x < 64) {
    x4p[((size_t)b * 8 + seg) * 256 + c] = fmaxf(fmaxf(red[0][cl], red[1][cl]), fmaxf(red[2][cl], red[3][cl]));
  }
}

// ---------------- xg = lrelu(bn(x4 @ w5^T)) ----------------
__global__ __launch_bounds__(256) void xg_kernel(const float* __restrict__ x4p, const float* __restrict__ w5,
    const float* __restrict__ g5, const float* __restrict__ b5, ushort_t* __restrict__ xgo) {
  __shared__ float x4l[256];
  const int b = blockIdx.x, tid = threadIdx.x;
  float v = x4p[(size_t)b * 2048 + tid];
#pragma unroll
  for (int s2 = 1; s2 < 8; ++s2) v = fmaxf(v, x4p[(size_t)b * 2048 + s2 * 256 + tid]);
  x4l[tid] = v;
  __syncthreads();
  const int lane = tid & 63, wave = tid >> 6;
  const float4 xv = *(const float4*)&x4l[lane * 4];
#pragma unroll 1
  for (int o = wave; o < 1024; o += 4) {
    const float4 w = *(const float4*)(w5 + (size_t)o * 256 + lane * 4);
    float acc = xv.x * w.x + xv.y * w.y + xv.z * w.z + xv.w * w.w;
#pragma unroll
    for (int s = 1; s < 64; s <<= 1) acc += __shfl_xor(acc, s, 64);
    if (lane == 0) {
      const float z = lrelu(acc * (g5[o] * RS) + b5[o]);
      const unsigned short h = f2bf(z);
      xgo[(size_t)b * 1024 + o] = h;
      xgo[XG_PO + (size_t)b * 1024 + o] = f2bf(z - bf2f(h));
    }
  }
}

// ---------------- final 256->2 + transpose to (B,2,N) ----------------
__global__ __launch_bounds__(256) void l3_kernel(const float* __restrict__ h6, const float* __restrict__ l3w,
    const float* __restrict__ l3b, float* __restrict__ out) {
  __shared__ float wl[512];
  const int tid = threadIdx.x;
  wl[tid] = l3w[tid]; wl[256 + tid] = l3w[256 + tid];
  __syncthreads();
  const int m = blockIdx.x * 256 + tid;
  float a0 = 0.f, a1 = 0.f;
#pragma unroll
  for (int c = 0; c < 256; c += 4) {
    const float4 h = *(const float4*)(h6 + (size_t)m * 256 + c);
    a0 += h.x * wl[c] + h.y * wl[c + 1] + h.z * wl[c + 2] + h.w * wl[c + 3];
    a1 += h.x * wl[256 + c] + h.y * wl[256 + c + 1] + h.z * wl[256 + c + 2] + h.w * wl[256 + c + 3];
  }
  const int b = m >> 12, n = m & 4095;
  out[(size_t)b * 8192 + n] = a0 + l3b[0];
  out[(size_t)b * 8192 + 4096 + n] = a1 + l3b[1];
}

extern "C" void kernel_launch(void* const* d_in, const int* in_sizes, int n_in,
                              void* d_out, int out_size, void* d_ws, size_t ws_size,
                              hipStream_t stream) {
  const float* x   = (const float*)d_in[0];
  const float* w1  = (const float*)d_in[2];
  const float* g1  = (const float*)d_in[3];
  const float* b1  = (const float*)d_in[4];
  const float* w2  = (const float*)d_in[5];
  const float* g2  = (const float*)d_in[6];
  const float* b2  = (const float*)d_in[7];
  const float* w3  = (const float*)d_in[8];
  const float* g3  = (const float*)d_in[9];
  const float* b3  = (const float*)d_in[10];
  const float* w4  = (const float*)d_in[11];
  const float* g4  = (const float*)d_in[12];
  const float* b4  = (const float*)d_in[13];
  const float* w5  = (const float*)d_in[14];
  const float* g5  = (const float*)d_in[15];
  const float* b5  = (const float*)d_in[16];
  const float* l1w = (const float*)d_in[17];
  const float* l1b = (const float*)d_in[18];
  const float* g6  = (const float*)d_in[19];
  const float* b6  = (const float*)d_in[20];
  const float* l2w = (const float*)d_in[21];
  const float* l2b = (const float*)d_in[22];
  const float* g7  = (const float*)d_in[23];
  const float* b7  = (const float*)d_in[24];
  const float* l3w = (const float*)d_in[25];
  const float* l3b = (const float*)d_in[26];
  float* outp = (float*)d_out;

  char* ws = (char*)d_ws;
  int*      idx  = (int*)(ws + 0);
  ushort_t* x1   = (ushort_t*)(ws + 2621440);
  ushort_t* x2   = (ushort_t*)(ws + 11010048);
  ushort_t* x3   = (ushort_t*)(ws + 27787264);
  float*    x4p  = (float*)(ws + 61341696);
  ushort_t* xgp  = (ushort_t*)(ws + 61407232);
  ushort_t* w3fp = (ushort_t*)(ws + 61440000);
  ushort_t* w4p  = (ushort_t*)(ws + 61472768);
  ushort_t* l2wp = (ushort_t*)(ws + 61603840);
  ushort_t* l1wp = (ushort_t*)(ws + 62128128);
  ushort_t* h5   = (ushort_t*)(ws + 65142784);
  float*    h6   = (float*)(ws + 11010048);  // overlays x2/x3 (dead after l1 gemm)

  knn_kernel<<<NPID / 4, 256, 0, stream>>>(x, idx);
  prep_kernel<<<3617, 256, 0, stream>>>(w3, w4, l1w, l2w, w3fp, w4p, l1wp, l2wp);
  edge_kernel<<<NPID / 4, 256, 0, stream>>>(x, idx, w1, g1, b1, w2, g2, b2, x1);
  // x2 = lrelu(bn(x1 @ w3f^T))      M=32768 K=64  O=128
  gemm_bf16<0, 0><<<256, 256, 0, stream>>>(x1, w3fp, x2, 64, 128, 1, X1_PO, 8192, X2_PO,
                                           g3, b3, nullptr, 1, nullptr, nullptr, nullptr, nullptr);
  // x3 = lrelu(bn(x2 @ w4^T))       K=128 O=256
  gemm_bf16<0, 0><<<512, 256, 0, stream>>>(x2, w4p, x3, 128, 256, 2, X2_PO, 32768, X3_PO,
                                           g4, b4, nullptr, 1, nullptr, nullptr, nullptr, nullptr);
  max_kernel<<<256, 256, 0, stream>>>(x3, x4p);
  xg_kernel<<<8, 256, 0, stream>>>(x4p, w5, g5, b5, xgp);
  // h5 = lrelu(bn(feat @ l1w^T + l1b))  K=1472 O=512  (concat gather)
  gemm_bf16<1, 0><<<1024, 256, 0, stream>>>(nullptr, l1wp, h5, 1472, 512, 4, 0, 753664, 16777216,
                                            g6, b6, l1b, 1, xgp, x3, x2, x1);
  // h6 = lrelu(bn(h5 @ l2w^T + l2b))    K=512 O=256  -> f32
  gemm_bf16<0, 1><<<512, 256, 0, stream>>>(h5, l2wp, h6, 512, 256, 2, 16777216, 131072, 0,
                                           g7, b7, l2b, 1, nullptr, nullptr, nullptr, nullptr);
  l3_kernel<<<128, 256, 0, stream>>>(h6, l3w, l3b, outp);
}

// Round 4
// 923.922 us; speedup vs baseline: 2.2932x; 1.0064x over previous
//
#include <hip/hip_runtime.h>

// ColorGradientNet on MI355X — round 4: kNN distance pass reads LDS-staged xyz tiles
// (2 x 2048 pts, global_load_lds staged, shared by 4 waves/block); ballot-compaction
// replaces LDS atomics. Threshold+bitonic selection unchanged (bit-exact vs reference).
// GEMMs: split-bf16 MFMA (hi/lo, 3-MFMA ~f32 accuracy), unchanged from round 2.
// Workspace layout (bytes):
//   idx  @ 0          : 32768*20 int32                  = 2,621,440
//   x1   @ 2621440    : 2 planes x 2,097,152 ushort     = 8,388,608
//   x2   @ 11010048   : 2 x 4,194,304 ushort            = 16,777,216
//   x3   @ 27787264   : 2 x 8,388,608 ushort            = 33,554,432
//   x4p  @ 61341696   : 8*8*256 f32                     = 65,536
//   xg   @ 61407232   : 2 x 8,192 ushort                = 32,768
//   w3f  @ 61440000   : 2 x 8,192 ushort                = 32,768
//   w4p  @ 61472768   : 2 x 32,768 ushort               = 131,072
//   l2wp @ 61603840   : 2 x 131,072 ushort              = 524,288
//   l1wp @ 62128128   : 2 x 753,664 ushort              = 3,014,656
//   h5   @ 65142784   : 2 x 16,777,216 ushort           = 67,108,864  (end 132,251,648)
//   h6   @ 11010048   : 32768*256 f32 (overlays x2/x3 — dead after l1 gemm)

#define KNN 20
#define NPID 32768
#define RS 0.99999500003750f  // 1/sqrt(1+1e-5)

// concat-source plane offsets (elements)
#define XG_PO 8192
#define X3_PO 8388608
#define X2_PO 4194304
#define X1_PO 2097152

typedef unsigned short ushort_t;
typedef __attribute__((ext_vector_type(8))) short bf16x8;
typedef __attribute__((ext_vector_type(4))) float f32x4;

#define LDS_PTR(p) ((__attribute__((address_space(3))) void*)(p))
#define GLB_PTR(p) ((const __attribute__((address_space(1))) void*)(p))

__device__ __forceinline__ float lrelu(float z) { return z >= 0.f ? z : 0.2f * z; }
__device__ __forceinline__ unsigned short f2bf(float f) {
  unsigned int u = __float_as_uint(f);
  return (unsigned short)((u + 0x7fffu + ((u >> 16) & 1u)) >> 16);
}
__device__ __forceinline__ float bf2f(unsigned short h) { return __uint_as_float((unsigned int)h << 16); }

// ---------------- kNN: LDS-staged distances + threshold + bitonic ----------------
// Distances replicate the reference f32 op order exactly (no FMA contraction), so the
// selected neighbor SET matches numpy bit-for-bit (downstream max-over-k is set-invariant).
// d[] index j -> candidate m = (j>>5)*2048 + (j&31)*64 + lane.
__global__ __launch_bounds__(256) void knn_kernel(const float* __restrict__ x, int* __restrict__ idxo) {
  __shared__ __align__(16) float pl[3][2048];  // staged tile: x,y,z planes (24 KB)
  __shared__ float cval[4][64];
  __shared__ int cidx[4][64];
  const int tid = threadIdx.x, lane = tid & 63, wave = tid >> 6;
  const int pid = blockIdx.x * 4 + wave;
  const int b = pid >> 12, n = pid & 4095;
  const float* xb = x + (size_t)b * 40960;
  const float px = xb[n], py = xb[4096 + n], pz = xb[8192 + n];
  const float xxn = __fadd_rn(__fadd_rn(__fmul_rn(px, px), __fmul_rn(py, py)), __fmul_rn(pz, pz));
  float d[64];
  float lmax = -3.4e38f;
#pragma unroll 1
  for (int t = 0; t < 2; ++t) {
    if (t) __syncthreads();  // all waves done reading previous tile
    // stage 2048 pts x 3 planes = 1536 float4, 24 chunks of 64 f4; chunk = r*4+wave
#pragma unroll
    for (int r = 0; r < 6; ++r) {
      const int q = (r * 4 + wave) * 64 + lane;          // f4 index in [0,1536)
      const int p = q >> 9, f = q & 511;                 // plane, within-plane f4
      const float* src = xb + p * 4096 + t * 2048 + f * 4;
      __builtin_amdgcn_global_load_lds(GLB_PTR(src), LDS_PTR((char*)pl + (r * 4 + wave) * 1024), 16, 0, 0);
    }
    __syncthreads();
#pragma unroll
    for (int j = 0; j < 32; ++j) {
      const int ml = j * 64 + lane;
      const float qx = pl[0][ml], qy = pl[1][ml], qz = pl[2][ml];
      const float xxm = __fadd_rn(__fadd_rn(__fmul_rn(qx, qx), __fmul_rn(qy, qy)), __fmul_rn(qz, qz));
      const float inner = __fadd_rn(__fadd_rn(__fmul_rn(px, qx), __fmul_rn(py, qy)), __fmul_rn(pz, qz));
      const float pd = __fsub_rn(__fsub_rn(__fmul_rn(2.0f, inner), xxn), xxm);
      d[t * 32 + j] = pd;
      lmax = fmaxf(lmax, pd);
    }
  }
  // bitonic sort of the 64 lane maxima, descending (value only)
  float v = lmax;
#pragma unroll
  for (int k = 2; k <= 64; k <<= 1) {
#pragma unroll
    for (int j = k >> 1; j > 0; j >>= 1) {
      const float ov = __shfl_xor(v, j, 64);
      const bool keepMax = (((lane & k) == 0) == ((lane & j) == 0));
      v = keepMax ? fmaxf(v, ov) : fminf(v, ov);
    }
  }
  const float t0 = __shfl(v, 19, 64);  // lower bound on true 20th-largest (>=20 elems >= t0)
  // ballot-compact candidates >= t0 into per-wave LDS (j-major, lane-asc: deterministic)
  int base = 0;
#pragma unroll
  for (int j = 0; j < 64; ++j) {
    const bool take = (d[j] >= t0);
    const unsigned long long mk = __ballot(take);
    if (take) {
      const int pos = base + __popcll(mk & ((1ull << lane) - 1ull));
      if (pos < 64) {
        cval[wave][pos] = d[j];
        cidx[wave][pos] = ((j >> 5) << 11) + ((j & 31) << 6) + lane;
      }
    }
    base += (int)__popcll(mk);
  }
  const int C = base;  // wave-uniform
  int* out = idxo + (size_t)pid * KNN;
  if (C <= 64) {
    // pack (value desc, index asc) into one u64 key; lanes >= C get key 0 (sorts last)
    unsigned long long key = 0ull;
    if (lane < C) {
      const unsigned int u = __float_as_uint(cval[wave][lane]);
      const unsigned int ou = (u & 0x80000000u) ? ~u : (u | 0x80000000u);
      key = ((unsigned long long)ou << 32) | (unsigned long long)(0xFFFFFFFFu - (unsigned int)cidx[wave][lane]);
    }
#pragma unroll
    for (int k = 2; k <= 64; k <<= 1) {
#pragma unroll
      for (int j = k >> 1; j > 0; j >>= 1) {
        const unsigned long long ok = (unsigned long long)__shfl_xor((long long)key, j, 64);
        const bool keepMax = (((lane & k) == 0) == ((lane & j) == 0));
        const bool gt = key > ok;
        key = (keepMax == gt) ? key : ok;
      }
    }
    if (lane < KNN) out[lane] = (int)(0xFFFFFFFFu - (unsigned int)key);
  } else {
    // exact fallback (statistically never taken): iterative wave-argmax with removal
    unsigned long long used = 0ull;
#pragma unroll 1
    for (int it = 0; it < KNN; ++it) {
      float lv = -3.4e38f;
      int li = 1 << 30;
#pragma unroll
      for (int j = 0; j < 64; ++j) {
        if (!((used >> j) & 1ull) && d[j] > lv) {
          lv = d[j];
          li = ((j >> 5) << 11) + ((j & 31) << 6) + lane;
        }
      }
      float bv = lv;
      int bi = li;
#pragma unroll
      for (int s = 1; s < 64; s <<= 1) {
        const float ovv = __shfl_xor(bv, s, 64);
        const int oii = __shfl_xor(bi, s, 64);
        if (ovv > bv || (ovv == bv && oii < bi)) { bv = ovv; bi = oii; }
      }
      if (lane == 0) out[it] = bi;
      if ((bi & 63) == lane) {
        const int jg = ((bi >> 11) << 5) + ((bi & 2047) >> 6);
        used |= 1ull << jg;
      }
    }
  }
}

// ---------------- edge features + MLP1(9->64) + MLP2(64->64) + max over k ----------------
__global__ __launch_bounds__(256) void edge_kernel(const float* __restrict__ x, const int* __restrict__ idxi,
    const float* __restrict__ w1, const float* __restrict__ g1, const float* __restrict__ b1,
    const float* __restrict__ w2, const float* __restrict__ g2, const float* __restrict__ b2,
    ushort_t* __restrict__ x1o) {
  __shared__ float fl[4][KNN][12];
  __shared__ float h1l[4][KNN][64];
  const int tid = threadIdx.x, wave = tid >> 6, lane = tid & 63;
  const int pid = blockIdx.x * 4 + wave;
  const int b = pid >> 12, n = pid & 4095;
  const float* xb = x + (size_t)b * 40960;
  if (lane < KNN) {
    const float c0 = xb[n], c1 = xb[4096 + n], c2 = xb[8192 + n];
    const float c3 = xb[12288 + n], c4 = xb[16384 + n], c5 = xb[20480 + n];
    const int mi = idxi[(size_t)pid * KNN + lane];
    float* fr = fl[wave][lane];
    fr[0] = c0; fr[1] = c1; fr[2] = c2;
    fr[3] = c3; fr[4] = c4; fr[5] = c5;
    fr[6] = c3 - xb[12288 + mi];
    fr[7] = c4 - xb[16384 + mi];
    fr[8] = c5 - xb[20480 + mi];
  }
  float w1r[9];
#pragma unroll
  for (int c = 0; c < 9; ++c) w1r[c] = w1[lane * 9 + c];
  const float s1 = g1[lane] * RS, t1 = b1[lane];
  __syncthreads();
#pragma unroll 1
  for (int kk = 0; kk < KNN; ++kk) {
    float acc = 0.f;
#pragma unroll
    for (int c = 0; c < 9; ++c) acc += fl[wave][kk][c] * w1r[c];
    h1l[wave][kk][lane] = lrelu(acc * s1 + t1);
  }
  float w2r[64];
#pragma unroll
  for (int c = 0; c < 64; c += 4) *(float4*)&w2r[c] = *(const float4*)(w2 + lane * 64 + c);
  const float s2 = g2[lane] * RS, t2 = b2[lane];
  __syncthreads();
  float xmax = -3.4e38f;
#pragma unroll 1
  for (int kk = 0; kk < KNN; ++kk) {
    float acc = 0.f;
#pragma unroll
    for (int c = 0; c < 64; c += 4) {
      const float4 h = *(const float4*)&h1l[wave][kk][c];
      acc += h.x * w2r[c] + h.y * w2r[c + 1] + h.z * w2r[c + 2] + h.w * w2r[c + 3];
    }
    xmax = fmaxf(xmax, lrelu(acc * s2 + t2));
  }
  const unsigned short h = f2bf(xmax);
  x1o[(size_t)pid * 64 + lane] = h;
  x1o[X1_PO + (size_t)pid * 64 + lane] = f2bf(xmax - bf2f(h));
}

// ---------------- weight prep: fold w3 + split all weights to bf16 hi/lo ----------------
__global__ __launch_bounds__(256) void prep_kernel(const float* __restrict__ w3, const float* __restrict__ w4,
    const float* __restrict__ l1w, const float* __restrict__ l2w,
    ushort_t* __restrict__ w3fp, ushort_t* __restrict__ w4p,
    ushort_t* __restrict__ l1wp, ushort_t* __restrict__ l2wp) {
  const int i = blockIdx.x * 256 + threadIdx.x;  // 0 .. 925695
  float f; ushort_t* hp; int n, j;
  if (i < 8192) {            // w3 folded: concat([x1,x1]) input
    const int o = i >> 6, c = i & 63;
    f = w3[o * 128 + c] + w3[o * 128 + 64 + c];
    hp = w3fp; n = 8192; j = i;
  } else if (i < 8192 + 32768) {
    j = i - 8192; f = w4[j]; hp = w4p; n = 32768;
  } else if (i < 8192 + 32768 + 131072) {
    j = i - 8192 - 32768; f = l2w[j]; hp = l2wp; n = 131072;
  } else if (i < 8192 + 32768 + 131072 + 753664) {
    j = i - 8192 - 32768 - 131072; f = l1w[j]; hp = l1wp; n = 753664;
  } else return;
  const unsigned short h = f2bf(f);
  hp[j] = h;
  hp[n + j] = f2bf(f - bf2f(h));
}

// ---------------- split-bf16 MFMA GEMM: out[m][o] = epi( A[m,:] . W[o,:] ) ----------------
// 128x128 tile, BK=64, 4 waves (64x64 each). LDS planes Ah|Al|Bh|Bl, each [128][64] bf16,
// XOR slot-swizzle (slot ^= row&7), staged by global_load_lds w16 with pre-swizzled source.
// MODE 0: A = hi plane (+aPO lo). MODE 1: gather concat [xg(1024)|x3(256)|x2(128)|x1(64)].
// OUTF32 0: out = bf16 hi plane (+outPO lo). OUTF32 1: out = f32.
template <int MODE, int OUTF32>
__global__ __launch_bounds__(256) void gemm_bf16(
    const ushort_t* __restrict__ A, const ushort_t* __restrict__ W, void* __restrict__ outv,
    const int Ktot, const int Nout, const int n_tiles,
    const int aPO, const int wPO, const int outPO,
    const float* __restrict__ gg, const float* __restrict__ bb,
    const float* __restrict__ linb, const int do_lrelu,
    const ushort_t* __restrict__ xg, const ushort_t* __restrict__ x3,
    const ushort_t* __restrict__ x2, const ushort_t* __restrict__ x1) {
  __shared__ __align__(16) ushort_t lds[32768];  // 64 KiB: 4 planes x [128][64]
  const int tid = threadIdx.x, lane = tid & 63, wid = tid >> 6;
  const int nwg = gridDim.x;
  int id = (blockIdx.x & 7) * (nwg >> 3) + (blockIdx.x >> 3);  // bijective XCD swizzle
  const int mt = id / n_tiles, nt = id - mt * n_tiles;         // n-tile fast: A-panel L2 reuse
  const int m0 = mt * 128, o0 = nt * 128;
  const int fr = lane & 15, kg = lane >> 4;
  const int wr = wid >> 1, wc = wid & 1;
  const int srow = lane >> 3, sslot = lane & 7;
  int rA[4], rB[4];
#pragma unroll
  for (int i = 0; i < 4; ++i) { rA[i] = wr * 64 + i * 16 + fr; rB[i] = wc * 64 + i * 16 + fr; }
  f32x4 acc[4][4] = {};
  const ushort_t* srcB = (wid == 2) ? W : W + wPO;               // planes 2,3
  const ushort_t* srcA0 = (MODE == 0) ? ((wid == 0) ? A : A + aPO) : nullptr;
  const int pl = (wid == 1);                                     // MODE 1 lo-plane flag

  for (int kc = 0; kc < Ktot; kc += 64) {
#pragma unroll
    for (int c = 0; c < 16; ++c) {
      const int row = c * 8 + srow;
      const int rslot = sslot ^ (row & 7);
      const int k = kc + rslot * 8;
      const ushort_t* q;
      if (wid >= 2) {
        q = srcB + (size_t)(o0 + row) * Ktot + k;
      } else if (MODE == 0) {
        q = srcA0 + (size_t)(m0 + row) * Ktot + k;
      } else {
        const int m = m0 + row;
        if (k < 1024)      q = xg + pl * XG_PO + ((m >> 12) << 10) + k;
        else if (k < 1280) q = x3 + pl * X3_PO + (size_t)m * 256 + (k - 1024);
        else if (k < 1408) q = x2 + pl * X2_PO + (size_t)m * 128 + (k - 1280);
        else               q = x1 + pl * X1_PO + (size_t)m * 64 + (k - 1408);
      }
      __builtin_amdgcn_global_load_lds(GLB_PTR(q), LDS_PTR(&lds[wid * 8192 + c * 512]), 16, 0, 0);
    }
    __syncthreads();
#pragma unroll
    for (int k0 = 0; k0 < 64; k0 += 32) {
      const int ks = (k0 >> 3) + kg;
      bf16x8 ah[4], al[4], bh[4], bl[4];
#pragma unroll
      for (int i = 0; i < 4; ++i) {
        const int off = rA[i] * 64 + ((ks ^ (rA[i] & 7)) << 3);
        ah[i] = *(const bf16x8*)&lds[off];
        al[i] = *(const bf16x8*)&lds[8192 + off];
      }
#pragma unroll
      for (int j = 0; j < 4; ++j) {
        const int off = rB[j] * 64 + ((ks ^ (rB[j] & 7)) << 3);
        bh[j] = *(const bf16x8*)&lds[16384 + off];
        bl[j] = *(const bf16x8*)&lds[24576 + off];
      }
#pragma unroll
      for (int i = 0; i < 4; ++i)
#pragma unroll
        for (int j = 0; j < 4; ++j) {
          acc[i][j] = __builtin_amdgcn_mfma_f32_16x16x32_bf16(ah[i], bh[j], acc[i][j], 0, 0, 0);
          acc[i][j] = __builtin_amdgcn_mfma_f32_16x16x32_bf16(ah[i], bl[j], acc[i][j], 0, 0, 0);
          acc[i][j] = __builtin_amdgcn_mfma_f32_16x16x32_bf16(al[i], bh[j], acc[i][j], 0, 0, 0);
        }
    }
    __syncthreads();
  }
  float s[4], t[4];
#pragma unroll
  for (int j = 0; j < 4; ++j) {
    const int o = o0 + wc * 64 + j * 16 + fr;
    s[j] = gg[o] * RS;
    t[j] = bb[o] + (linb ? linb[o] * s[j] : 0.f);
  }
#pragma unroll
  for (int i = 0; i < 4; ++i) {
#pragma unroll
    for (int j = 0; j < 4; ++j) {
      const int col = o0 + wc * 64 + j * 16 + fr;
#pragma unroll
      for (int r = 0; r < 4; ++r) {
        const int row = m0 + wr * 64 + i * 16 + kg * 4 + r;
        float z = acc[i][j][r] * s[j] + t[j];
        if (do_lrelu) z = lrelu(z);
        if (OUTF32) {
          ((float*)outv)[(size_t)row * Nout + col] = z;
        } else {
          ushort_t* oh = (ushort_t*)outv;
          const unsigned short h = f2bf(z);
          oh[(size_t)row * Nout + col] = h;
          oh[outPO + (size_t)row * Nout + col] = f2bf(z - bf2f(h));
        }
      }
    }
  }
}

// ---------------- max over N (partial, 8 segments); x3 is bf16 hi/lo ----------------
__global__ __launch_bounds__(256) void max_kernel(const ushort_t* __restrict__ x3, float* __restrict__ x4p) {
  __shared__ float red[4][64];
  const int bid = blockIdx.x;  // 8b * 8seg * 4q
  const int q = bid & 3, seg = (bid >> 2) & 7, b = bid >> 5;
  const int cl = threadIdx.x & 63, nl = threadIdx.x >> 6;
  const int c = (q << 6) + cl;
  float acc = -3.4e38f;
  const int n0 = seg * 512;
  for (int n = n0 + nl; n < n0 + 512; n += 4) {
    const size_t e = ((size_t)b * 4096 + n) * 256 + c;
    acc = fmaxf(acc, bf2f(x3[e]) + bf2f(x3[X3_PO + e]));
  }
  red[nl][cl] = acc;
  __syncthreads();
  if (threadIdx.x < 64) {
    x4p[((size_t)b * 8 + seg) * 256 + c] = fmaxf(fmaxf(red[0][cl], red[1][cl]), fmaxf(red[2][cl], red[3][cl]));
  }
}

// ---------------- xg = lrelu(bn(x4 @ w5^T)) ----------------
__global__ __launch_bounds__(256) void xg_kernel(const float* __restrict__ x4p, const float* __restrict__ w5,
    const float* __restrict__ g5, const float* __restrict__ b5, ushort_t* __restrict__ xgo) {
  __shared__ float x4l[256];
  const int b = blockIdx.x, tid = threadIdx.x;
  float v = x4p[(size_t)b * 2048 + tid];
#pragma unroll
  for (int s2 = 1; s2 < 8; ++s2) v = fmaxf(v, x4p[(size_t)b * 2048 + s2 * 256 + tid]);
  x4l[tid] = v;
  __syncthreads();
  const int lane = tid & 63, wave = tid >> 6;
  const float4 xv = *(const float4*)&x4l[lane * 4];
#pragma unroll 1
  for (int o = wave; o < 1024; o += 4) {
    const float4 w = *(const float4*)(w5 + (size_t)o * 256 + lane * 4);
    float acc = xv.x * w.x + xv.y * w.y + xv.z * w.z + xv.w * w.w;
#pragma unroll
    for (int s = 1; s < 64; s <<= 1) acc += __shfl_xor(acc, s, 64);
    if (lane == 0) {
      const float z = lrelu(acc * (g5[o] * RS) + b5[o]);
      const unsigned short h = f2bf(z);
      xgo[(size_t)b * 1024 + o] = h;
      xgo[XG_PO + (size_t)b * 1024 + o] = f2bf(z - bf2f(h));
    }
  }
}

// ---------------- final 256->2 + transpose to (B,2,N) ----------------
__global__ __launch_bounds__(256) void l3_kernel(const float* __restrict__ h6, const float* __restrict__ l3w,
    const float* __restrict__ l3b, float* __restrict__ out) {
  __shared__ float wl[512];
  const int tid = threadIdx.x;
  wl[tid] = l3w[tid]; wl[256 + tid] = l3w[256 + tid];
  __syncthreads();
  const int m = blockIdx.x * 256 + tid;
  float a0 = 0.f, a1 = 0.f;
#pragma unroll
  for (int c = 0; c < 256; c += 4) {
    const float4 h = *(const float4*)(h6 + (size_t)m * 256 + c);
    a0 += h.x * wl[c] + h.y * wl[c + 1] + h.z * wl[c + 2] + h.w * wl[c + 3];
    a1 += h.x * wl[256 + c] + h.y * wl[256 + c + 1] + h.z * wl[256 + c + 2] + h.w * wl[256 + c + 3];
  }
  const int b = m >> 12, n = m & 4095;
  out[(size_t)b * 8192 + n] = a0 + l3b[0];
  out[(size_t)b * 8192 + 4096 + n] = a1 + l3b[1];
}

extern "C" void kernel_launch(void* const* d_in, const int* in_sizes, int n_in,
                              void* d_out, int out_size, void* d_ws, size_t ws_size,
                              hipStream_t stream) {
  const float* x   = (const float*)d_in[0];
  const float* w1  = (const float*)d_in[2];
  const float* g1  = (const float*)d_in[3];
  const float* b1  = (const float*)d_in[4];
  const float* w2  = (const float*)d_in[5];
  const float* g2  = (const float*)d_in[6];
  const float* b2  = (const float*)d_in[7];
  const float* w3  = (const float*)d_in[8];
  const float* g3  = (const float*)d_in[9];
  const float* b3  = (const float*)d_in[10];
  const float* w4  = (const float*)d_in[11];
  const float* g4  = (const float*)d_in[12];
  const float* b4  = (const float*)d_in[13];
  const float* w5  = (const float*)d_in[14];
  const float* g5  = (const float*)d_in[15];
  const float* b5  = (const float*)d_in[16];
  const float* l1w = (const float*)d_in[17];
  const float* l1b = (const float*)d_in[18];
  const float* g6  = (const float*)d_in[19];
  const float* b6  = (const float*)d_in[20];
  const float* l2w = (const float*)d_in[21];
  const float* l2b = (const float*)d_in[22];
  const float* g7  = (const float*)d_in[23];
  const float* b7  = (const float*)d_in[24];
  const float* l3w = (const float*)d_in[25];
  const float* l3b = (const float*)d_in[26];
  float* outp = (float*)d_out;

  char* ws = (char*)d_ws;
  int*      idx  = (int*)(ws + 0);
  ushort_t* x1   = (ushort_t*)(ws + 2621440);
  ushort_t* x2   = (ushort_t*)(ws + 11010048);
  ushort_t* x3   = (ushort_t*)(ws + 27787264);
  float*    x4p  = (float*)(ws + 61341696);
  ushort_t* xgp  = (ushort_t*)(ws + 61407232);
  ushort_t* w3fp = (ushort_t*)(ws + 61440000);
  ushort_t* w4p  = (ushort_t*)(ws + 61472768);
  ushort_t* l2wp = (ushort_t*)(ws + 61603840);
  ushort_t* l1wp = (ushort_t*)(ws + 62128128);
  ushort_t* h5   = (ushort_t*)(ws + 65142784);
  float*    h6   = (float*)(ws + 11010048);  // overlays x2/x3 (dead after l1 gemm)

  knn_kernel<<<NPID / 4, 256, 0, stream>>>(x, idx);
  prep_kernel<<<3617, 256, 0, stream>>>(w3, w4, l1w, l2w, w3fp, w4p, l1wp, l2wp);
  edge_kernel<<<NPID / 4, 256, 0, stream>>>(x, idx, w1, g1, b1, w2, g2, b2, x1);
  // x2 = lrelu(bn(x1 @ w3f^T))      M=32768 K=64  O=128
  gemm_bf16<0, 0><<<256, 256, 0, stream>>>(x1, w3fp, x2, 64, 128, 1, X1_PO, 8192, X2_PO,
                                           g3, b3, nullptr, 1, nullptr, nullptr, nullptr, nullptr);
  // x3 = lrelu(bn(x2 @ w4^T))       K=128 O=256
  gemm_bf16<0, 0><<<512, 256, 0, stream>>>(x2, w4p, x3, 128, 256, 2, X2_PO, 32768, X3_PO,
                                           g4, b4, nullptr, 1, nullptr, nullptr, nullptr, nullptr);
  max_kernel<<<256, 256, 0, stream>>>(x3, x4p);
  xg_kernel<<<8, 256, 0, stream>>>(x4p, w5, g5, b5, xgp);
  // h5 = lrelu(bn(feat @ l1w^T + l1b))  K=1472 O=512  (concat gather)
  gemm_bf16<1, 0><<<1024, 256, 0, stream>>>(nullptr, l1wp, h5, 1472, 512, 4, 0, 753664, 16777216,
                                            g6, b6, l1b, 1, xgp, x3, x2, x1);
  // h6 = lrelu(bn(h5 @ l2w^T + l2b))    K=512 O=256  -> f32
  gemm_bf16<0, 1><<<512, 256, 0, stream>>>(h5, l2wp, h6, 512, 256, 2, 16777216, 131072, 0,
                                           g7, b7, l2b, 1, nullptr, nullptr, nullptr, nullptr);
  l3_kernel<<<128, 256, 0, stream>>>(h6, l3w, l3b, outp);
}

// Round 5
// 735.990 us; speedup vs baseline: 2.8788x; 1.2553x over previous
//
#include <hip/hip_runtime.h>

// ColorGradientNet on MI355X — round 5:
//  * knn: fix rule-#20 scratch spill (fully unroll tile loop -> d[] stays in VGPRs)
//  * edge: 8 independent FMA chains in MLP2 (unroll-2 x 4 accumulators) — latency fix
// GEMMs: split-bf16 MFMA (hi/lo, 3-MFMA ~f32 accuracy), unchanged.
// Workspace layout (bytes):
//   idx  @ 0          : 32768*20 int32                  = 2,621,440
//   x1   @ 2621440    : 2 planes x 2,097,152 ushort     = 8,388,608
//   x2   @ 11010048   : 2 x 4,194,304 ushort            = 16,777,216
//   x3   @ 27787264   : 2 x 8,388,608 ushort            = 33,554,432
//   x4p  @ 61341696   : 8*8*256 f32                     = 65,536
//   xg   @ 61407232   : 2 x 8,192 ushort                = 32,768
//   w3f  @ 61440000   : 2 x 8,192 ushort                = 32,768
//   w4p  @ 61472768   : 2 x 32,768 ushort               = 131,072
//   l2wp @ 61603840   : 2 x 131,072 ushort              = 524,288
//   l1wp @ 62128128   : 2 x 753,664 ushort              = 3,014,656
//   h5   @ 65142784   : 2 x 16,777,216 ushort           = 67,108,864  (end 132,251,648)
//   h6   @ 11010048   : 32768*256 f32 (overlays x2/x3 — dead after l1 gemm)

#define KNN 20
#define NPID 32768
#define RS 0.99999500003750f  // 1/sqrt(1+1e-5)

// concat-source plane offsets (elements)
#define XG_PO 8192
#define X3_PO 8388608
#define X2_PO 4194304
#define X1_PO 2097152

typedef unsigned short ushort_t;
typedef __attribute__((ext_vector_type(8))) short bf16x8;
typedef __attribute__((ext_vector_type(4))) float f32x4;

#define LDS_PTR(p) ((__attribute__((address_space(3))) void*)(p))
#define GLB_PTR(p) ((const __attribute__((address_space(1))) void*)(p))

__device__ __forceinline__ float lrelu(float z) { return z >= 0.f ? z : 0.2f * z; }
__device__ __forceinline__ unsigned short f2bf(float f) {
  unsigned int u = __float_as_uint(f);
  return (unsigned short)((u + 0x7fffu + ((u >> 16) & 1u)) >> 16);
}
__device__ __forceinline__ float bf2f(unsigned short h) { return __uint_as_float((unsigned int)h << 16); }

// ---------------- kNN: LDS-staged distances + threshold + bitonic ----------------
// Distances replicate the reference f32 op order exactly (no FMA contraction), so the
// selected neighbor SET matches numpy bit-for-bit (downstream max-over-k is set-invariant).
// d[] index j -> candidate m = (j>>5)*2048 + (j&31)*64 + lane.
__global__ __launch_bounds__(256) void knn_kernel(const float* __restrict__ x, int* __restrict__ idxo) {
  __shared__ __align__(16) float pl[3][2048];  // staged tile: x,y,z planes (24 KB)
  __shared__ float cval[4][64];
  __shared__ int cidx[4][64];
  const int tid = threadIdx.x, lane = tid & 63, wave = tid >> 6;
  const int pid = blockIdx.x * 4 + wave;
  const int b = pid >> 12, n = pid & 4095;
  const float* xb = x + (size_t)b * 40960;
  const float px = xb[n], py = xb[4096 + n], pz = xb[8192 + n];
  const float xxn = __fadd_rn(__fadd_rn(__fmul_rn(px, px), __fmul_rn(py, py)), __fmul_rn(pz, pz));
  float d[64];
  float lmax = -3.4e38f;
#pragma unroll                    // FULL unroll: t must be compile-time (rule #20!)
  for (int t = 0; t < 2; ++t) {
    if (t) __syncthreads();  // all waves done reading previous tile
    // stage 2048 pts x 3 planes = 1536 float4, 24 chunks of 64 f4; chunk = r*4+wave
#pragma unroll
    for (int r = 0; r < 6; ++r) {
      const int q = (r * 4 + wave) * 64 + lane;          // f4 index in [0,1536)
      const int p = q >> 9, f = q & 511;                 // plane, within-plane f4
      const float* src = xb + p * 4096 + t * 2048 + f * 4;
      __builtin_amdgcn_global_load_lds(GLB_PTR(src), LDS_PTR((char*)pl + (r * 4 + wave) * 1024), 16, 0, 0);
    }
    __syncthreads();
#pragma unroll
    for (int j = 0; j < 32; ++j) {
      const int ml = j * 64 + lane;
      const float qx = pl[0][ml], qy = pl[1][ml], qz = pl[2][ml];
      const float xxm = __fadd_rn(__fadd_rn(__fmul_rn(qx, qx), __fmul_rn(qy, qy)), __fmul_rn(qz, qz));
      const float inner = __fadd_rn(__fadd_rn(__fmul_rn(px, qx), __fmul_rn(py, qy)), __fmul_rn(pz, qz));
      const float pd = __fsub_rn(__fsub_rn(__fmul_rn(2.0f, inner), xxn), xxm);
      d[t * 32 + j] = pd;
      lmax = fmaxf(lmax, pd);
    }
  }
  // bitonic sort of the 64 lane maxima, descending (value only)
  float v = lmax;
#pragma unroll
  for (int k = 2; k <= 64; k <<= 1) {
#pragma unroll
    for (int j = k >> 1; j > 0; j >>= 1) {
      const float ov = __shfl_xor(v, j, 64);
      const bool keepMax = (((lane & k) == 0) == ((lane & j) == 0));
      v = keepMax ? fmaxf(v, ov) : fminf(v, ov);
    }
  }
  const float t0 = __shfl(v, 19, 64);  // lower bound on true 20th-largest (>=20 elems >= t0)
  // ballot-compact candidates >= t0 into per-wave LDS (j-major, lane-asc: deterministic)
  int base = 0;
#pragma unroll
  for (int j = 0; j < 64; ++j) {
    const bool take = (d[j] >= t0);
    const unsigned long long mk = __ballot(take);
    if (take) {
      const int pos = base + __popcll(mk & ((1ull << lane) - 1ull));
      if (pos < 64) {
        cval[wave][pos] = d[j];
        cidx[wave][pos] = ((j >> 5) << 11) + ((j & 31) << 6) + lane;
      }
    }
    base += (int)__popcll(mk);
  }
  const int C = base;  // wave-uniform
  int* out = idxo + (size_t)pid * KNN;
  if (C <= 64) {
    // pack (value desc, index asc) into one u64 key; lanes >= C get key 0 (sorts last)
    unsigned long long key = 0ull;
    if (lane < C) {
      const unsigned int u = __float_as_uint(cval[wave][lane]);
      const unsigned int ou = (u & 0x80000000u) ? ~u : (u | 0x80000000u);
      key = ((unsigned long long)ou << 32) | (unsigned long long)(0xFFFFFFFFu - (unsigned int)cidx[wave][lane]);
    }
#pragma unroll
    for (int k = 2; k <= 64; k <<= 1) {
#pragma unroll
      for (int j = k >> 1; j > 0; j >>= 1) {
        const unsigned long long ok = (unsigned long long)__shfl_xor((long long)key, j, 64);
        const bool keepMax = (((lane & k) == 0) == ((lane & j) == 0));
        const bool gt = key > ok;
        key = (keepMax == gt) ? key : ok;
      }
    }
    if (lane < KNN) out[lane] = (int)(0xFFFFFFFFu - (unsigned int)key);
  } else {
    // exact fallback (statistically never taken): iterative wave-argmax with removal
    unsigned long long used = 0ull;
#pragma unroll 1
    for (int it = 0; it < KNN; ++it) {
      float lv = -3.4e38f;
      int li = 1 << 30;
#pragma unroll
      for (int j = 0; j < 64; ++j) {
        if (!((used >> j) & 1ull) && d[j] > lv) {
          lv = d[j];
          li = ((j >> 5) << 11) + ((j & 31) << 6) + lane;
        }
      }
      float bv = lv;
      int bi = li;
#pragma unroll
      for (int s = 1; s < 64; s <<= 1) {
        const float ovv = __shfl_xor(bv, s, 64);
        const int oii = __shfl_xor(bi, s, 64);
        if (ovv > bv || (ovv == bv && oii < bi)) { bv = ovv; bi = oii; }
      }
      if (lane == 0) out[it] = bi;
      if ((bi & 63) == lane) {
        const int jg = ((bi >> 11) << 5) + ((bi & 2047) >> 6);
        used |= 1ull << jg;
      }
    }
  }
}

// ---------------- edge features + MLP1(9->64) + MLP2(64->64) + max over k ----------------
__global__ __launch_bounds__(256) void edge_kernel(const float* __restrict__ x, const int* __restrict__ idxi,
    const float* __restrict__ w1, const float* __restrict__ g1, const float* __restrict__ b1,
    const float* __restrict__ w2, const float* __restrict__ g2, const float* __restrict__ b2,
    ushort_t* __restrict__ x1o) {
  __shared__ float fl[4][KNN][12];
  __shared__ float h1l[4][KNN][64];
  const int tid = threadIdx.x, wave = tid >> 6, lane = tid & 63;
  const int pid = blockIdx.x * 4 + wave;
  const int b = pid >> 12, n = pid & 4095;
  const float* xb = x + (size_t)b * 40960;
  if (lane < KNN) {
    const float c0 = xb[n], c1 = xb[4096 + n], c2 = xb[8192 + n];
    const float c3 = xb[12288 + n], c4 = xb[16384 + n], c5 = xb[20480 + n];
    const int mi = idxi[(size_t)pid * KNN + lane];
    float* fr = fl[wave][lane];
    fr[0] = c0; fr[1] = c1; fr[2] = c2;
    fr[3] = c3; fr[4] = c4; fr[5] = c5;
    fr[6] = c3 - xb[12288 + mi];
    fr[7] = c4 - xb[16384 + mi];
    fr[8] = c5 - xb[20480 + mi];
  }
  float w1r[9];
#pragma unroll
  for (int c = 0; c < 9; ++c) w1r[c] = w1[lane * 9 + c];
  const float s1 = g1[lane] * RS, t1 = b1[lane];
  __syncthreads();
#pragma unroll
  for (int kk = 0; kk < KNN; ++kk) {
    float acc = 0.f;
#pragma unroll
    for (int c = 0; c < 9; ++c) acc += fl[wave][kk][c] * w1r[c];
    h1l[wave][kk][lane] = lrelu(acc * s1 + t1);
  }
  float w2r[64];
#pragma unroll
  for (int c = 0; c < 64; c += 4) *(float4*)&w2r[c] = *(const float4*)(w2 + lane * 64 + c);
  const float s2 = g2[lane] * RS, t2 = b2[lane];
  __syncthreads();
  float xmax = -3.4e38f;
#pragma unroll 2
  for (int kk = 0; kk < KNN; ++kk) {
    float a0 = 0.f, a1 = 0.f, a2 = 0.f, a3 = 0.f;  // 4 chains (reassociation OK: threshold slack)
#pragma unroll
    for (int c = 0; c < 64; c += 16) {
      const float4 h0 = *(const float4*)&h1l[wave][kk][c];
      const float4 h1v = *(const float4*)&h1l[wave][kk][c + 4];
      const float4 h2v = *(const float4*)&h1l[wave][kk][c + 8];
      const float4 h3v = *(const float4*)&h1l[wave][kk][c + 12];
      a0 += h0.x * w2r[c] + h0.y * w2r[c + 1] + h0.z * w2r[c + 2] + h0.w * w2r[c + 3];
      a1 += h1v.x * w2r[c + 4] + h1v.y * w2r[c + 5] + h1v.z * w2r[c + 6] + h1v.w * w2r[c + 7];
      a2 += h2v.x * w2r[c + 8] + h2v.y * w2r[c + 9] + h2v.z * w2r[c + 10] + h2v.w * w2r[c + 11];
      a3 += h3v.x * w2r[c + 12] + h3v.y * w2r[c + 13] + h3v.z * w2r[c + 14] + h3v.w * w2r[c + 15];
    }
    const float acc = (a0 + a1) + (a2 + a3);
    xmax = fmaxf(xmax, lrelu(acc * s2 + t2));
  }
  const unsigned short h = f2bf(xmax);
  x1o[(size_t)pid * 64 + lane] = h;
  x1o[X1_PO + (size_t)pid * 64 + lane] = f2bf(xmax - bf2f(h));
}

// ---------------- weight prep: fold w3 + split all weights to bf16 hi/lo ----------------
__global__ __launch_bounds__(256) void prep_kernel(const float* __restrict__ w3, const float* __restrict__ w4,
    const float* __restrict__ l1w, const float* __restrict__ l2w,
    ushort_t* __restrict__ w3fp, ushort_t* __restrict__ w4p,
    ushort_t* __restrict__ l1wp, ushort_t* __restrict__ l2wp) {
  const int i = blockIdx.x * 256 + threadIdx.x;  // 0 .. 925695
  float f; ushort_t* hp; int n, j;
  if (i < 8192) {            // w3 folded: concat([x1,x1]) input
    const int o = i >> 6, c = i & 63;
    f = w3[o * 128 + c] + w3[o * 128 + 64 + c];
    hp = w3fp; n = 8192; j = i;
  } else if (i < 8192 + 32768) {
    j = i - 8192; f = w4[j]; hp = w4p; n = 32768;
  } else if (i < 8192 + 32768 + 131072) {
    j = i - 8192 - 32768; f = l2w[j]; hp = l2wp; n = 131072;
  } else if (i < 8192 + 32768 + 131072 + 753664) {
    j = i - 8192 - 32768 - 131072; f = l1w[j]; hp = l1wp; n = 753664;
  } else return;
  const unsigned short h = f2bf(f);
  hp[j] = h;
  hp[n + j] = f2bf(f - bf2f(h));
}

// ---------------- split-bf16 MFMA GEMM: out[m][o] = epi( A[m,:] . W[o,:] ) ----------------
// 128x128 tile, BK=64, 4 waves (64x64 each). LDS planes Ah|Al|Bh|Bl, each [128][64] bf16,
// XOR slot-swizzle (slot ^= row&7), staged by global_load_lds w16 with pre-swizzled source.
// MODE 0: A = hi plane (+aPO lo). MODE 1: gather concat [xg(1024)|x3(256)|x2(128)|x1(64)].
// OUTF32 0: out = bf16 hi plane (+outPO lo). OUTF32 1: out = f32.
template <int MODE, int OUTF32>
__global__ __launch_bounds__(256) void gemm_bf16(
    const ushort_t* __restrict__ A, const ushort_t* __restrict__ W, void* __restrict__ outv,
    const int Ktot, const int Nout, const int n_tiles,
    const int aPO, const int wPO, const int outPO,
    const float* __restrict__ gg, const float* __restrict__ bb,
    const float* __restrict__ linb, const int do_lrelu,
    const ushort_t* __restrict__ xg, const ushort_t* __restrict__ x3,
    const ushort_t* __restrict__ x2, const ushort_t* __restrict__ x1) {
  __shared__ __align__(16) ushort_t lds[32768];  // 64 KiB: 4 planes x [128][64]
  const int tid = threadIdx.x, lane = tid & 63, wid = tid >> 6;
  const int nwg = gridDim.x;
  int id = (blockIdx.x & 7) * (nwg >> 3) + (blockIdx.x >> 3);  // bijective XCD swizzle
  const int mt = id / n_tiles, nt = id - mt * n_tiles;         // n-tile fast: A-panel L2 reuse
  const int m0 = mt * 128, o0 = nt * 128;
  const int fr = lane & 15, kg = lane >> 4;
  const int wr = wid >> 1, wc = wid & 1;
  const int srow = lane >> 3, sslot = lane & 7;
  int rA[4], rB[4];
#pragma unroll
  for (int i = 0; i < 4; ++i) { rA[i] = wr * 64 + i * 16 + fr; rB[i] = wc * 64 + i * 16 + fr; }
  f32x4 acc[4][4] = {};
  const ushort_t* srcB = (wid == 2) ? W : W + wPO;               // planes 2,3
  const ushort_t* srcA0 = (MODE == 0) ? ((wid == 0) ? A : A + aPO) : nullptr;
  const int pl = (wid == 1);                                     // MODE 1 lo-plane flag

  for (int kc = 0; kc < Ktot; kc += 64) {
#pragma unroll
    for (int c = 0; c < 16; ++c) {
      const int row = c * 8 + srow;
      const int rslot = sslot ^ (row & 7);
      const int k = kc + rslot * 8;
      const ushort_t* q;
      if (wid >= 2) {
        q = srcB + (size_t)(o0 + row) * Ktot + k;
      } else if (MODE == 0) {
        q = srcA0 + (size_t)(m0 + row) * Ktot + k;
      } else {
        const int m = m0 + row;
        if (k < 1024)      q = xg + pl * XG_PO + ((m >> 12) << 10) + k;
        else if (k < 1280) q = x3 + pl * X3_PO + (size_t)m * 256 + (k - 1024);
        else if (k < 1408) q = x2 + pl * X2_PO + (size_t)m * 128 + (k - 1280);
        else               q = x1 + pl * X1_PO + (size_t)m * 64 + (k - 1408);
      }
      __builtin_amdgcn_global_load_lds(GLB_PTR(q), LDS_PTR(&lds[wid * 8192 + c * 512]), 16, 0, 0);
    }
    __syncthreads();
#pragma unroll
    for (int k0 = 0; k0 < 64; k0 += 32) {
      const int ks = (k0 >> 3) + kg;
      bf16x8 ah[4], al[4], bh[4], bl[4];
#pragma unroll
      for (int i = 0; i < 4; ++i) {
        const int off = rA[i] * 64 + ((ks ^ (rA[i] & 7)) << 3);
        ah[i] = *(const bf16x8*)&lds[off];
        al[i] = *(const bf16x8*)&lds[8192 + off];
      }
#pragma unroll
      for (int j = 0; j < 4; ++j) {
        const int off = rB[j] * 64 + ((ks ^ (rB[j] & 7)) << 3);
        bh[j] = *(const bf16x8*)&lds[16384 + off];
        bl[j] = *(const bf16x8*)&lds[24576 + off];
      }
#pragma unroll
      for (int i = 0; i < 4; ++i)
#pragma unroll
        for (int j = 0; j < 4; ++j) {
          acc[i][j] = __builtin_amdgcn_mfma_f32_16x16x32_bf16(ah[i], bh[j], acc[i][j], 0, 0, 0);
          acc[i][j] = __builtin_amdgcn_mfma_f32_16x16x32_bf16(ah[i], bl[j], acc[i][j], 0, 0, 0);
          acc[i][j] = __builtin_amdgcn_mfma_f32_16x16x32_bf16(al[i], bh[j], acc[i][j], 0, 0, 0);
        }
    }
    __syncthreads();
  }
  float s[4], t[4];
#pragma unroll
  for (int j = 0; j < 4; ++j) {
    const int o = o0 + wc * 64 + j * 16 + fr;
    s[j] = gg[o] * RS;
    t[j] = bb[o] + (linb ? linb[o] * s[j] : 0.f);
  }
#pragma unroll
  for (int i = 0; i < 4; ++i) {
#pragma unroll
    for (int j = 0; j < 4; ++j) {
      const int col = o0 + wc * 64 + j * 16 + fr;
#pragma unroll
      for (int r = 0; r < 4; ++r) {
        const int row = m0 + wr * 64 + i * 16 + kg * 4 + r;
        float z = acc[i][j][r] * s[j] + t[j];
        if (do_lrelu) z = lrelu(z);
        if (OUTF32) {
          ((float*)outv)[(size_t)row * Nout + col] = z;
        } else {
          ushort_t* oh = (ushort_t*)outv;
          const unsigned short h = f2bf(z);
          oh[(size_t)row * Nout + col] = h;
          oh[outPO + (size_t)row * Nout + col] = f2bf(z - bf2f(h));
        }
      }
    }
  }
}

// ---------------- max over N (partial, 8 segments); x3 is bf16 hi/lo ----------------
__global__ __launch_bounds__(256) void max_kernel(const ushort_t* __restrict__ x3, float* __restrict__ x4p) {
  __shared__ float red[4][64];
  const int bid = blockIdx.x;  // 8b * 8seg * 4q
  const int q = bid & 3, seg = (bid >> 2) & 7, b = bid >> 5;
  const int cl = threadIdx.x & 63, nl = threadIdx.x >> 6;
  const int c = (q << 6) + cl;
  float acc = -3.4e38f;
  const int n0 = seg * 512;
  for (int n = n0 + nl; n < n0 + 512; n += 4) {
    const size_t e = ((size_t)b * 4096 + n) * 256 + c;
    acc = fmaxf(acc, bf2f(x3[e]) + bf2f(x3[X3_PO + e]));
  }
  red[nl][cl] = acc;
  __syncthreads();
  if (threadIdx.x < 64) {
    x4p[((size_t)b * 8 + seg) * 256 + c] = fmaxf(fmaxf(red[0][cl], red[1][cl]), fmaxf(red[2][cl], red[3][cl]));
  }
}

// ---------------- xg = lrelu(bn(x4 @ w5^T)) ----------------
__global__ __launch_bounds__(256) void xg_kernel(const float* __restrict__ x4p, const float* __restrict__ w5,
    const float* __restrict__ g5, const float* __restrict__ b5, ushort_t* __restrict__ xgo) {
  __shared__ float x4l[256];
  const int b = blockIdx.x, tid = threadIdx.x;
  float v = x4p[(size_t)b * 2048 + tid];
#pragma unroll
  for (int s2 = 1; s2 < 8; ++s2) v = fmaxf(v, x4p[(size_t)b * 2048 + s2 * 256 + tid]);
  x4l[tid] = v;
  __syncthreads();
  const int lane = tid & 63, wave = tid >> 6;
  const float4 xv = *(const float4*)&x4l[lane * 4];
#pragma unroll 1
  for (int o = wave; o < 1024; o += 4) {
    const float4 w = *(const float4*)(w5 + (size_t)o * 256 + lane * 4);
    float acc = xv.x * w.x + xv.y * w.y + xv.z * w.z + xv.w * w.w;
#pragma unroll
    for (int s = 1; s < 64; s <<= 1) acc += __shfl_xor(acc, s, 64);
    if (lane == 0) {
      const float z = lrelu(acc * (g5[o] * RS) + b5[o]);
      const unsigned short h = f2bf(z);
      xgo[(size_t)b * 1024 + o] = h;
      xgo[XG_PO + (size_t)b * 1024 + o] = f2bf(z - bf2f(h));
    }
  }
}

// ---------------- final 256->2 + transpose to (B,2,N) ----------------
__global__ __launch_bounds__(256) void l3_kernel(const float* __restrict__ h6, const float* __restrict__ l3w,
    const float* __restrict__ l3b, float* __restrict__ out) {
  __shared__ float wl[512];
  const int tid = threadIdx.x;
  wl[tid] = l3w[tid]; wl[256 + tid] = l3w[256 + tid];
  __syncthreads();
  const int m = blockIdx.x * 256 + tid;
  float a0 = 0.f, a1 = 0.f;
#pragma unroll
  for (int c = 0; c < 256; c += 4) {
    const float4 h = *(const float4*)(h6 + (size_t)m * 256 + c);
    a0 += h.x * wl[c] + h.y * wl[c + 1] + h.z * wl[c + 2] + h.w * wl[c + 3];
    a1 += h.x * wl[256 + c] + h.y * wl[256 + c + 1] + h.z * wl[256 + c + 2] + h.w * wl[256 + c + 3];
  }
  const int b = m >> 12, n = m & 4095;
  out[(size_t)b * 8192 + n] = a0 + l3b[0];
  out[(size_t)b * 8192 + 4096 + n] = a1 + l3b[1];
}

extern "C" void kernel_launch(void* const* d_in, const int* in_sizes, int n_in,
                              void* d_out, int out_size, void* d_ws, size_t ws_size,
                              hipStream_t stream) {
  const float* x   = (const float*)d_in[0];
  const float* w1  = (const float*)d_in[2];
  const float* g1  = (const float*)d_in[3];
  const float* b1  = (const float*)d_in[4];
  const float* w2  = (const float*)d_in[5];
  const float* g2  = (const float*)d_in[6];
  const float* b2  = (const float*)d_in[7];
  const float* w3  = (const float*)d_in[8];
  const float* g3  = (const float*)d_in[9];
  const float* b3  = (const float*)d_in[10];
  const float* w4  = (const float*)d_in[11];
  const float* g4  = (const float*)d_in[12];
  const float* b4  = (const float*)d_in[13];
  const float* w5  = (const float*)d_in[14];
  const float* g5  = (const float*)d_in[15];
  const float* b5  = (const float*)d_in[16];
  const float* l1w = (const float*)d_in[17];
  const float* l1b = (const float*)d_in[18];
  const float* g6  = (const float*)d_in[19];
  const float* b6  = (const float*)d_in[20];
  const float* l2w = (const float*)d_in[21];
  const float* l2b = (const float*)d_in[22];
  const float* g7  = (const float*)d_in[23];
  const float* b7  = (const float*)d_in[24];
  const float* l3w = (const float*)d_in[25];
  const float* l3b = (const float*)d_in[26];
  float* outp = (float*)d_out;

  char* ws = (char*)d_ws;
  int*      idx  = (int*)(ws + 0);
  ushort_t* x1   = (ushort_t*)(ws + 2621440);
  ushort_t* x2   = (ushort_t*)(ws + 11010048);
  ushort_t* x3   = (ushort_t*)(ws + 27787264);
  float*    x4p  = (float*)(ws + 61341696);
  ushort_t* xgp  = (ushort_t*)(ws + 61407232);
  ushort_t* w3fp = (ushort_t*)(ws + 61440000);
  ushort_t* w4p  = (ushort_t*)(ws + 61472768);
  ushort_t* l2wp = (ushort_t*)(ws + 61603840);
  ushort_t* l1wp = (ushort_t*)(ws + 62128128);
  ushort_t* h5   = (ushort_t*)(ws + 65142784);
  float*    h6   = (float*)(ws + 11010048);  // overlays x2/x3 (dead after l1 gemm)

  knn_kernel<<<NPID / 4, 256, 0, stream>>>(x, idx);
  prep_kernel<<<3617, 256, 0, stream>>>(w3, w4, l1w, l2w, w3fp, w4p, l1wp, l2wp);
  edge_kernel<<<NPID / 4, 256, 0, stream>>>(x, idx, w1, g1, b1, w2, g2, b2, x1);
  // x2 = lrelu(bn(x1 @ w3f^T))      M=32768 K=64  O=128
  gemm_bf16<0, 0><<<256, 256, 0, stream>>>(x1, w3fp, x2, 64, 128, 1, X1_PO, 8192, X2_PO,
                                           g3, b3, nullptr, 1, nullptr, nullptr, nullptr, nullptr);
  // x3 = lrelu(bn(x2 @ w4^T))       K=128 O=256
  gemm_bf16<0, 0><<<512, 256, 0, stream>>>(x2, w4p, x3, 128, 256, 2, X2_PO, 32768, X3_PO,
                                           g4, b4, nullptr, 1, nullptr, nullptr, nullptr, nullptr);
  max_kernel<<<256, 256, 0, stream>>>(x3, x4p);
  xg_kernel<<<8, 256, 0, stream>>>(x4p, w5, g5, b5, xgp);
  // h5 = lrelu(bn(feat @ l1w^T + l1b))  K=1472 O=512  (concat gather)
  gemm_bf16<1, 0><<<1024, 256, 0, stream>>>(nullptr, l1wp, h5, 1472, 512, 4, 0, 753664, 16777216,
                                            g6, b6, l1b, 1, xgp, x3, x2, x1);
  // h6 = lrelu(bn(h5 @ l2w^T + l2b))    K=512 O=256  -> f32
  gemm_bf16<0, 1><<<512, 256, 0, stream>>>(h5, l2wp, h6, 512, 256, 2, 16777216, 131072, 0,
                                           g7, b7, l2b, 1, nullptr, nullptr, nullptr, nullptr);
  l3_kernel<<<128, 256, 0, stream>>>(h6, l3w, l3b, outp);
}

// Round 6
// 572.211 us; speedup vs baseline: 3.7028x; 1.2862x over previous
//
#include <hip/hip_runtime.h>

// ColorGradientNet on MI355X — round 6: edge MLP moved to MFMA.
//  * 1 wave = 16 points; h1 = 1 MFMA/16ch via 27-slot split packing
//    (A=[fh|fh|fl|0], B=[wh|wl|wh|0] -> ah.bh+ah.bl+al.bh in ONE mfma);
//    h1 -> swizzled per-wave LDS transpose -> h2 = 3-MFMA split; max in C-frags.
//  * w2 pre-split hi/lo by prep_kernel (stored in x4p region — disjoint live range).
// knn / GEMMs unchanged from round 5.
// Workspace layout (bytes):
//   idx  @ 0          : 32768*20 int32                  = 2,621,440
//   x1   @ 2621440    : 2 planes x 2,097,152 ushort     = 8,388,608
//   x2   @ 11010048   : 2 x 4,194,304 ushort            = 16,777,216
//   x3   @ 27787264   : 2 x 8,388,608 ushort            = 33,554,432
//   w2p  @ 61341696   : 2 x 4,096 ushort (16 KB, overlays x4p: w2p live [prep,edge], x4p live [max,xg])
//   x4p  @ 61341696   : 8*8*256 f32                     = 65,536
//   xg   @ 61407232   : 2 x 8,192 ushort                = 32,768
//   w3f  @ 61440000   : 2 x 8,192 ushort                = 32,768
//   w4p  @ 61472768   : 2 x 32,768 ushort               = 131,072
//   l2wp @ 61603840   : 2 x 131,072 ushort              = 524,288
//   l1wp @ 62128128   : 2 x 753,664 ushort              = 3,014,656
//   h5   @ 65142784   : 2 x 16,777,216 ushort           = 67,108,864  (end 132,251,648)
//   h6   @ 11010048   : 32768*256 f32 (overlays x2/x3 — dead after l1 gemm)

#define KNN 20
#define NPID 32768
#define RS 0.99999500003750f  // 1/sqrt(1+1e-5)

// concat-source plane offsets (elements)
#define XG_PO 8192
#define X3_PO 8388608
#define X2_PO 4194304
#define X1_PO 2097152

typedef unsigned short ushort_t;
typedef unsigned int u32;
typedef __attribute__((ext_vector_type(8))) short bf16x8;
typedef __attribute__((ext_vector_type(4))) float f32x4;

#define LDS_PTR(p) ((__attribute__((address_space(3))) void*)(p))
#define GLB_PTR(p) ((const __attribute__((address_space(1))) void*)(p))

__device__ __forceinline__ float lrelu(float z) { return z >= 0.f ? z : 0.2f * z; }
__device__ __forceinline__ unsigned short f2bf(float f) {
  unsigned int u = __float_as_uint(f);
  return (unsigned short)((u + 0x7fffu + ((u >> 16) & 1u)) >> 16);
}
__device__ __forceinline__ float bf2f(unsigned short h) { return __uint_as_float((unsigned int)h << 16); }
__device__ __forceinline__ u32 pack2(u32 e0, u32 e1) { return (e1 << 16) | (e0 & 0xffffu); }
__device__ __forceinline__ f32x4 mfma16(uint4 a, uint4 b, f32x4 c) {
  return __builtin_amdgcn_mfma_f32_16x16x32_bf16(
      __builtin_bit_cast(bf16x8, a), __builtin_bit_cast(bf16x8, b), c, 0, 0, 0);
}

// ---------------- kNN: LDS-staged distances + threshold + bitonic ----------------
__global__ __launch_bounds__(256) void knn_kernel(const float* __restrict__ x, int* __restrict__ idxo) {
  __shared__ __align__(16) float pl[3][2048];
  __shared__ float cval[4][64];
  __shared__ int cidx[4][64];
  const int tid = threadIdx.x, lane = tid & 63, wave = tid >> 6;
  const int pid = blockIdx.x * 4 + wave;
  const int b = pid >> 12, n = pid & 4095;
  const float* xb = x + (size_t)b * 40960;
  const float px = xb[n], py = xb[4096 + n], pz = xb[8192 + n];
  const float xxn = __fadd_rn(__fadd_rn(__fmul_rn(px, px), __fmul_rn(py, py)), __fmul_rn(pz, pz));
  float d[64];
  float lmax = -3.4e38f;
#pragma unroll
  for (int t = 0; t < 2; ++t) {
    if (t) __syncthreads();
#pragma unroll
    for (int r = 0; r < 6; ++r) {
      const int q = (r * 4 + wave) * 64 + lane;
      const int p = q >> 9, f = q & 511;
      const float* src = xb + p * 4096 + t * 2048 + f * 4;
      __builtin_amdgcn_global_load_lds(GLB_PTR(src), LDS_PTR((char*)pl + (r * 4 + wave) * 1024), 16, 0, 0);
    }
    __syncthreads();
#pragma unroll
    for (int j = 0; j < 32; ++j) {
      const int ml = j * 64 + lane;
      const float qx = pl[0][ml], qy = pl[1][ml], qz = pl[2][ml];
      const float xxm = __fadd_rn(__fadd_rn(__fmul_rn(qx, qx), __fmul_rn(qy, qy)), __fmul_rn(qz, qz));
      const float inner = __fadd_rn(__fadd_rn(__fmul_rn(px, qx), __fmul_rn(py, qy)), __fmul_rn(pz, qz));
      const float pd = __fsub_rn(__fsub_rn(__fmul_rn(2.0f, inner), xxn), xxm);
      d[t * 32 + j] = pd;
      lmax = fmaxf(lmax, pd);
    }
  }
  float v = lmax;
#pragma unroll
  for (int k = 2; k <= 64; k <<= 1) {
#pragma unroll
    for (int j = k >> 1; j > 0; j >>= 1) {
      const float ov = __shfl_xor(v, j, 64);
      const bool keepMax = (((lane & k) == 0) == ((lane & j) == 0));
      v = keepMax ? fmaxf(v, ov) : fminf(v, ov);
    }
  }
  const float t0 = __shfl(v, 19, 64);
  int base = 0;
#pragma unroll
  for (int j = 0; j < 64; ++j) {
    const bool take = (d[j] >= t0);
    const unsigned long long mk = __ballot(take);
    if (take) {
      const int pos = base + __popcll(mk & ((1ull << lane) - 1ull));
      if (pos < 64) {
        cval[wave][pos] = d[j];
        cidx[wave][pos] = ((j >> 5) << 11) + ((j & 31) << 6) + lane;
      }
    }
    base += (int)__popcll(mk);
  }
  const int C = base;
  int* out = idxo + (size_t)pid * KNN;
  if (C <= 64) {
    unsigned long long key = 0ull;
    if (lane < C) {
      const unsigned int u = __float_as_uint(cval[wave][lane]);
      const unsigned int ou = (u & 0x80000000u) ? ~u : (u | 0x80000000u);
      key = ((unsigned long long)ou << 32) | (unsigned long long)(0xFFFFFFFFu - (unsigned int)cidx[wave][lane]);
    }
#pragma unroll
    for (int k = 2; k <= 64; k <<= 1) {
#pragma unroll
      for (int j = k >> 1; j > 0; j >>= 1) {
        const unsigned long long ok = (unsigned long long)__shfl_xor((long long)key, j, 64);
        const bool keepMax = (((lane & k) == 0) == ((lane & j) == 0));
        const bool gt = key > ok;
        key = (keepMax == gt) ? key : ok;
      }
    }
    if (lane < KNN) out[lane] = (int)(0xFFFFFFFFu - (unsigned int)key);
  } else {
    unsigned long long used = 0ull;
#pragma unroll 1
    for (int it = 0; it < KNN; ++it) {
      float lv = -3.4e38f;
      int li = 1 << 30;
#pragma unroll
      for (int j = 0; j < 64; ++j) {
        if (!((used >> j) & 1ull) && d[j] > lv) {
          lv = d[j];
          li = ((j >> 5) << 11) + ((j & 31) << 6) + lane;
        }
      }
      float bv = lv;
      int bi = li;
#pragma unroll
      for (int s = 1; s < 64; s <<= 1) {
        const float ovv = __shfl_xor(bv, s, 64);
        const int oii = __shfl_xor(bi, s, 64);
        if (ovv > bv || (ovv == bv && oii < bi)) { bv = ovv; bi = oii; }
      }
      if (lane == 0) out[it] = bi;
      if ((bi & 63) == lane) {
        const int jg = ((bi >> 11) << 5) + ((bi & 2047) >> 6);
        used |= 1ull << jg;
      }
    }
  }
}

// ---------------- edge: fused MFMA h1(9->64) + h2(64->64) + max over k ----------------
// 1 wave = 16 points. A-frag (16x16x32): lane(fr,kg) holds row fr, k-slots kg*8..+7.
// C-frag: lane holds row kg*4+r, col fr (verified mapping from passing GEMM).
__global__ __launch_bounds__(256) void edge_kernel(const float* __restrict__ x, const int* __restrict__ idxi,
    const float* __restrict__ w1, const float* __restrict__ g1, const float* __restrict__ b1,
    const ushort_t* __restrict__ w2p, const float* __restrict__ g2, const float* __restrict__ b2,
    ushort_t* __restrict__ x1o) {
  __shared__ u32 hstage[4][16][64];  // per-wave h1 transpose tile (hi<<16|lo), col XOR-swizzled
  const int tid = threadIdx.x, lane = tid & 63, wave = tid >> 6;
  const int fr = lane & 15, kg = lane >> 4;
  const int pbase = blockIdx.x * 64 + wave * 16;
  const int b = (blockIdx.x * 64) >> 12;
  const float* xq = x + (size_t)b * 40960;

  // ---- center features of this lane's A-row point (p = fr), hi/lo split ----
  const int nA = (pbase + fr) & 4095;
  float cv[6]; ushort_t chv[6], clv[6];
#pragma unroll
  for (int j = 0; j < 6; ++j) {
    cv[j] = xq[j * 4096 + nA];
    chv[j] = f2bf(cv[j]);
    clv[j] = f2bf(cv[j] - bf2f(chv[j]));
  }
  const float crv = cv[3], cgv = cv[4], cbv = cv[5];

  // constant parts of the A-frag (27-slot packing: [ah(9)|ah(9)|al(9)|0^5])
  u32 aC0 = 0, aC1 = 0, aC2 = 0, aC3 = 0;
  if (kg == 0) { aC0 = pack2(chv[0], chv[1]); aC1 = pack2(chv[2], chv[3]); aC2 = pack2(chv[4], chv[5]); }
  else if (kg == 1) { aC0 = (u32)chv[0] << 16; aC1 = pack2(chv[1], chv[2]); aC2 = pack2(chv[3], chv[4]); aC3 = chv[5]; }
  else if (kg == 2) { aC1 = pack2(clv[0], clv[1]); aC2 = pack2(clv[2], clv[3]); aC3 = pack2(clv[4], clv[5]); }

  // ---- bn params for this lane's 4 C-columns (ch = fj*16+fr) ----
  float s1v[4], t1v[4], s2v[4], t2v[4];
#pragma unroll
  for (int fj = 0; fj < 4; ++fj) {
    const int och = fj * 16 + fr;
    s1v[fj] = g1[och] * RS; t1v[fj] = b1[och];
    s2v[fj] = g2[och] * RS; t2v[fj] = b2[och];
  }

  // ---- w1 B-frags: B = [wh(9)|wl(9)|wh(9)|0^5] mirrored to A packing ----
  uint4 w1Bv[4];
#pragma unroll
  for (int fj = 0; fj < 4; ++fj) {
    const int och = fj * 16 + fr;
    ushort_t wh[9], wl[9];
#pragma unroll
    for (int j = 0; j < 9; ++j) {
      const float wv = w1[och * 9 + j];
      wh[j] = f2bf(wv);
      wl[j] = f2bf(wv - bf2f(wh[j]));
    }
    uint4 q;
    if (kg == 0)      { q.x = pack2(wh[0], wh[1]); q.y = pack2(wh[2], wh[3]); q.z = pack2(wh[4], wh[5]); q.w = pack2(wh[6], wh[7]); }
    else if (kg == 1) { q.x = pack2(wh[8], wl[0]); q.y = pack2(wl[1], wl[2]); q.z = pack2(wl[3], wl[4]); q.w = pack2(wl[5], wl[6]); }
    else if (kg == 2) { q.x = pack2(wl[7], wl[8]); q.y = pack2(wh[0], wh[1]); q.z = pack2(wh[2], wh[3]); q.w = pack2(wh[4], wh[5]); }
    else              { q.x = pack2(wh[6], wh[7]); q.y = pack2(wh[8], 0);     q.z = 0;                   q.w = 0; }
    w1Bv[fj] = q;
  }

  // ---- w2 B-frags from pre-split planes: lane needs och=fj*16+fr, k = sub*32+kg*8..+7 ----
  uint4 w2Bh[4][2], w2Bl[4][2];
#pragma unroll
  for (int fj = 0; fj < 4; ++fj) {
    const int och = fj * 16 + fr;
#pragma unroll
    for (int sub = 0; sub < 2; ++sub) {
      const ushort_t* ph = w2p + och * 64 + sub * 32 + kg * 8;
      w2Bh[fj][sub] = *(const uint4*)ph;
      w2Bl[fj][sub] = *(const uint4*)(ph + 4096);
    }
  }

  // ---- gather pipeline: idx depth-2, rgb depth-1 ----
  const int prow = (pbase + fr) * KNN;
  int miA = idxi[prow];
  int miN = idxi[prow + 1];
  float pr = xq[12288 + miA], pg = xq[16384 + miA], pb = xq[20480 + miA];

  f32x4 xm[4];
#pragma unroll
  for (int fj = 0; fj < 4; ++fj) { xm[fj][0] = -3.4e38f; xm[fj][1] = -3.4e38f; xm[fj][2] = -3.4e38f; xm[fj][3] = -3.4e38f; }
  const f32x4 zz = {0.f, 0.f, 0.f, 0.f};

#pragma unroll 1
  for (int kk = 0; kk < KNN; ++kk) {
    const float nrv = pr, ngv = pg, nbv = pb;
    if (kk < KNN - 1) { pr = xq[12288 + miN]; pg = xq[16384 + miN]; pb = xq[20480 + miN]; }
    if (kk < KNN - 2) { miN = idxi[prow + kk + 2]; }

    // rgb diffs, hi/lo split
    const float dr = crv - nrv, dg = cgv - ngv, db = cbv - nbv;
    const ushort_t drh = f2bf(dr), dgh = f2bf(dg), dbh = f2bf(db);
    const ushort_t drl = f2bf(dr - bf2f(drh)), dgl = f2bf(dg - bf2f(dgh)), dbl = f2bf(db - bf2f(dbh));

    // A-frag build (dynamic slots only)
    uint4 aF;
    if (kg == 0)      { aF.x = aC0; aF.y = aC1; aF.z = aC2; aF.w = pack2(drh, dgh); }
    else if (kg == 1) { aF.x = aC0 | dbh; aF.y = aC1; aF.z = aC2; aF.w = aC3 | ((u32)drh << 16); }
    else if (kg == 2) { aF.x = pack2(dgh, dbh); aF.y = aC1; aF.z = aC2; aF.w = aC3; }
    else              { aF.x = pack2(drl, dgl); aF.y = (u32)dbl; aF.z = 0; aF.w = 0; }

    // h1: one MFMA per 16 output channels (full split dot in-slot)
    f32x4 h1a[4];
#pragma unroll
    for (int fj = 0; fj < 4; ++fj) h1a[fj] = mfma16(aF, w1Bv[fj], zz);

    // h1 epilogue -> swizzled LDS transpose tile (no barrier: wave-private)
#pragma unroll
    for (int fj = 0; fj < 4; ++fj)
#pragma unroll
      for (int r = 0; r < 4; ++r) {
        float z = h1a[fj][r] * s1v[fj] + t1v[fj];
        z = fmaxf(z, 0.2f * z);  // lrelu
        const ushort_t hi = f2bf(z), lo = f2bf(z - bf2f(hi));
        const int pC = kg * 4 + r;
        hstage[wave][pC][(fj * 16 + fr) ^ ((pC & 7) << 3)] = ((u32)hi << 16) | lo;
      }

    // h2: read own row (point fr), 3-MFMA split per sub-K
    f32x4 a2[4] = {zz, zz, zz, zz};
#pragma unroll
    for (int sub = 0; sub < 2; ++sub) {
      const u32* rp = &hstage[wave][fr][(sub * 32 + kg * 8) ^ ((fr & 7) << 3)];
      const uint4 q0 = *(const uint4*)rp;
      const uint4 q1 = *(const uint4*)(rp + 4);
      uint4 ah, al;
      ah.x = __builtin_amdgcn_perm(q0.y, q0.x, 0x07060302u); al.x = __builtin_amdgcn_perm(q0.y, q0.x, 0x05040100u);
      ah.y = __builtin_amdgcn_perm(q0.w, q0.z, 0x07060302u); al.y = __builtin_amdgcn_perm(q0.w, q0.z, 0x05040100u);
      ah.z = __builtin_amdgcn_perm(q1.y, q1.x, 0x07060302u); al.z = __builtin_amdgcn_perm(q1.y, q1.x, 0x05040100u);
      ah.w = __builtin_amdgcn_perm(q1.w, q1.z, 0x07060302u); al.w = __builtin_amdgcn_perm(q1.w, q1.z, 0x05040100u);
#pragma unroll
      for (int fj = 0; fj < 4; ++fj) {
        a2[fj] = mfma16(ah, w2Bh[fj][sub], a2[fj]);
        a2[fj] = mfma16(ah, w2Bl[fj][sub], a2[fj]);
        a2[fj] = mfma16(al, w2Bh[fj][sub], a2[fj]);
      }
    }

    // h2 epilogue + running max
#pragma unroll
    for (int fj = 0; fj < 4; ++fj)
#pragma unroll
      for (int r = 0; r < 4; ++r) {
        float z = a2[fj][r] * s2v[fj] + t2v[fj];
        z = fmaxf(z, 0.2f * z);
        xm[fj][r] = fmaxf(xm[fj][r], z);
      }
  }

  // ---- store x1 (hi/lo planes); lane's C rows = pbase + kg*4 + r ----
#pragma unroll
  for (int fj = 0; fj < 4; ++fj)
#pragma unroll
    for (int r = 0; r < 4; ++r) {
      const size_t e = (size_t)(pbase + kg * 4 + r) * 64 + fj * 16 + fr;
      const float v = xm[fj][r];
      const ushort_t hi = f2bf(v);
      x1o[e] = hi;
      x1o[X1_PO + e] = f2bf(v - bf2f(hi));
    }
}

// ---------------- weight prep: fold w3 + split all weights to bf16 hi/lo ----------------
__global__ __launch_bounds__(256) void prep_kernel(const float* __restrict__ w3, const float* __restrict__ w4,
    const float* __restrict__ l1w, const float* __restrict__ l2w, const float* __restrict__ w2,
    ushort_t* __restrict__ w3fp, ushort_t* __restrict__ w4p,
    ushort_t* __restrict__ l1wp, ushort_t* __restrict__ l2wp, ushort_t* __restrict__ w2p) {
  const int i = blockIdx.x * 256 + threadIdx.x;  // 0 .. 929791
  float f; ushort_t* hp; int n, j;
  if (i < 8192) {            // w3 folded: concat([x1,x1]) input
    const int o = i >> 6, c = i & 63;
    f = w3[o * 128 + c] + w3[o * 128 + 64 + c];
    hp = w3fp; n = 8192; j = i;
  } else if (i < 8192 + 32768) {
    j = i - 8192; f = w4[j]; hp = w4p; n = 32768;
  } else if (i < 8192 + 32768 + 131072) {
    j = i - 8192 - 32768; f = l2w[j]; hp = l2wp; n = 131072;
  } else if (i < 8192 + 32768 + 131072 + 753664) {
    j = i - 8192 - 32768 - 131072; f = l1w[j]; hp = l1wp; n = 753664;
  } else if (i < 8192 + 32768 + 131072 + 753664 + 4096) {
    j = i - 925696; f = w2[j]; hp = w2p; n = 4096;
  } else return;
  const unsigned short h = f2bf(f);
  hp[j] = h;
  hp[n + j] = f2bf(f - bf2f(h));
}

// ---------------- split-bf16 MFMA GEMM (unchanged) ----------------
template <int MODE, int OUTF32>
__global__ __launch_bounds__(256) void gemm_bf16(
    const ushort_t* __restrict__ A, const ushort_t* __restrict__ W, void* __restrict__ outv,
    const int Ktot, const int Nout, const int n_tiles,
    const int aPO, const int wPO, const int outPO,
    const float* __restrict__ gg, const float* __restrict__ bb,
    const float* __restrict__ linb, const int do_lrelu,
    const ushort_t* __restrict__ xg, const ushort_t* __restrict__ x3,
    const ushort_t* __restrict__ x2, const ushort_t* __restrict__ x1) {
  __shared__ __align__(16) ushort_t lds[32768];
  const int tid = threadIdx.x, lane = tid & 63, wid = tid >> 6;
  const int nwg = gridDim.x;
  int id = (blockIdx.x & 7) * (nwg >> 3) + (blockIdx.x >> 3);
  const int mt = id / n_tiles, nt = id - mt * n_tiles;
  const int m0 = mt * 128, o0 = nt * 128;
  const int fr = lane & 15, kg = lane >> 4;
  const int wr = wid >> 1, wc = wid & 1;
  const int srow = lane >> 3, sslot = lane & 7;
  int rA[4], rB[4];
#pragma unroll
  for (int i = 0; i < 4; ++i) { rA[i] = wr * 64 + i * 16 + fr; rB[i] = wc * 64 + i * 16 + fr; }
  f32x4 acc[4][4] = {};
  const ushort_t* srcB = (wid == 2) ? W : W + wPO;
  const ushort_t* srcA0 = (MODE == 0) ? ((wid == 0) ? A : A + aPO) : nullptr;
  const int pl = (wid == 1);

  for (int kc = 0; kc < Ktot; kc += 64) {
#pragma unroll
    for (int c = 0; c < 16; ++c) {
      const int row = c * 8 + srow;
      const int rslot = sslot ^ (row & 7);
      const int k = kc + rslot * 8;
      const ushort_t* q;
      if (wid >= 2) {
        q = srcB + (size_t)(o0 + row) * Ktot + k;
      } else if (MODE == 0) {
        q = srcA0 + (size_t)(m0 + row) * Ktot + k;
      } else {
        const int m = m0 + row;
        if (k < 1024)      q = xg + pl * XG_PO + ((m >> 12) << 10) + k;
        else if (k < 1280) q = x3 + pl * X3_PO + (size_t)m * 256 + (k - 1024);
        else if (k < 1408) q = x2 + pl * X2_PO + (size_t)m * 128 + (k - 1280);
        else               q = x1 + pl * X1_PO + (size_t)m * 64 + (k - 1408);
      }
      __builtin_amdgcn_global_load_lds(GLB_PTR(q), LDS_PTR(&lds[wid * 8192 + c * 512]), 16, 0, 0);
    }
    __syncthreads();
#pragma unroll
    for (int k0 = 0; k0 < 64; k0 += 32) {
      const int ks = (k0 >> 3) + kg;
      bf16x8 ah[4], al[4], bh[4], bl[4];
#pragma unroll
      for (int i = 0; i < 4; ++i) {
        const int off = rA[i] * 64 + ((ks ^ (rA[i] & 7)) << 3);
        ah[i] = *(const bf16x8*)&lds[off];
        al[i] = *(const bf16x8*)&lds[8192 + off];
      }
#pragma unroll
      for (int j = 0; j < 4; ++j) {
        const int off = rB[j] * 64 + ((ks ^ (rB[j] & 7)) << 3);
        bh[j] = *(const bf16x8*)&lds[16384 + off];
        bl[j] = *(const bf16x8*)&lds[24576 + off];
      }
#pragma unroll
      for (int i = 0; i < 4; ++i)
#pragma unroll
        for (int j = 0; j < 4; ++j) {
          acc[i][j] = __builtin_amdgcn_mfma_f32_16x16x32_bf16(ah[i], bh[j], acc[i][j], 0, 0, 0);
          acc[i][j] = __builtin_amdgcn_mfma_f32_16x16x32_bf16(ah[i], bl[j], acc[i][j], 0, 0, 0);
          acc[i][j] = __builtin_amdgcn_mfma_f32_16x16x32_bf16(al[i], bh[j], acc[i][j], 0, 0, 0);
        }
    }
    __syncthreads();
  }
  float s[4], t[4];
#pragma unroll
  for (int j = 0; j < 4; ++j) {
    const int o = o0 + wc * 64 + j * 16 + fr;
    s[j] = gg[o] * RS;
    t[j] = bb[o] + (linb ? linb[o] * s[j] : 0.f);
  }
#pragma unroll
  for (int i = 0; i < 4; ++i) {
#pragma unroll
    for (int j = 0; j < 4; ++j) {
      const int col = o0 + wc * 64 + j * 16 + fr;
#pragma unroll
      for (int r = 0; r < 4; ++r) {
        const int row = m0 + wr * 64 + i * 16 + kg * 4 + r;
        float z = acc[i][j][r] * s[j] + t[j];
        if (do_lrelu) z = lrelu(z);
        if (OUTF32) {
          ((float*)outv)[(size_t)row * Nout + col] = z;
        } else {
          ushort_t* oh = (ushort_t*)outv;
          const unsigned short h = f2bf(z);
          oh[(size_t)row * Nout + col] = h;
          oh[outPO + (size_t)row * Nout + col] = f2bf(z - bf2f(h));
        }
      }
    }
  }
}

// ---------------- max over N (partial, 8 segments); x3 is bf16 hi/lo ----------------
__global__ __launch_bounds__(256) void max_kernel(const ushort_t* __restrict__ x3, float* __restrict__ x4p) {
  __shared__ float red[4][64];
  const int bid = blockIdx.x;
  const int q = bid & 3, seg = (bid >> 2) & 7, b = bid >> 5;
  const int cl = threadIdx.x & 63, nl = threadIdx.x >> 6;
  const int c = (q << 6) + cl;
  float acc = -3.4e38f;
  const int n0 = seg * 512;
  for (int n = n0 + nl; n < n0 + 512; n += 4) {
    const size_t e = ((size_t)b * 4096 + n) * 256 + c;
    acc = fmaxf(acc, bf2f(x3[e]) + bf2f(x3[X3_PO + e]));
  }
  red[nl][cl] = acc;
  __syncthreads();
  if (threadIdx.x < 64) {
    x4p[((size_t)b * 8 + seg) * 256 + c] = fmaxf(fmaxf(red[0][cl], red[1][cl]), fmaxf(red[2][cl], red[3][cl]));
  }
}

// ---------------- xg = lrelu(bn(x4 @ w5^T)) ----------------
__global__ __launch_bounds__(256) void xg_kernel(const float* __restrict__ x4p, const float* __restrict__ w5,
    const float* __restrict__ g5, const float* __restrict__ b5, ushort_t* __restrict__ xgo) {
  __shared__ float x4l[256];
  const int b = blockIdx.x, tid = threadIdx.x;
  float v = x4p[(size_t)b * 2048 + tid];
#pragma unroll
  for (int s2 = 1; s2 < 8; ++s2) v = fmaxf(v, x4p[(size_t)b * 2048 + s2 * 256 + tid]);
  x4l[tid] = v;
  __syncthreads();
  const int lane = tid & 63, wave = tid >> 6;
  const float4 xv = *(const float4*)&x4l[lane * 4];
#pragma unroll 1
  for (int o = wave; o < 1024; o += 4) {
    const float4 w = *(const float4*)(w5 + (size_t)o * 256 + lane * 4);
    float acc = xv.x * w.x + xv.y * w.y + xv.z * w.z + xv.w * w.w;
#pragma unroll
    for (int s = 1; s < 64; s <<= 1) acc += __shfl_xor(acc, s, 64);
    if (lane == 0) {
      const float z = lrelu(acc * (g5[o] * RS) + b5[o]);
      const unsigned short h = f2bf(z);
      xgo[(size_t)b * 1024 + o] = h;
      xgo[XG_PO + (size_t)b * 1024 + o] = f2bf(z - bf2f(h));
    }
  }
}

// ---------------- final 256->2 + transpose to (B,2,N) ----------------
__global__ __launch_bounds__(256) void l3_kernel(const float* __restrict__ h6, const float* __restrict__ l3w,
    const float* __restrict__ l3b, float* __restrict__ out) {
  __shared__ float wl[512];
  const int tid = threadIdx.x;
  wl[tid] = l3w[tid]; wl[256 + tid] = l3w[256 + tid];
  __syncthreads();
  const int m = blockIdx.x * 256 + tid;
  float a0 = 0.f, a1 = 0.f;
#pragma unroll
  for (int c = 0; c < 256; c += 4) {
    const float4 h = *(const float4*)(h6 + (size_t)m * 256 + c);
    a0 += h.x * wl[c] + h.y * wl[c + 1] + h.z * wl[c + 2] + h.w * wl[c + 3];
    a1 += h.x * wl[256 + c] + h.y * wl[256 + c + 1] + h.z * wl[256 + c + 2] + h.w * wl[256 + c + 3];
  }
  const int b = m >> 12, n = m & 4095;
  out[(size_t)b * 8192 + n] = a0 + l3b[0];
  out[(size_t)b * 8192 + 4096 + n] = a1 + l3b[1];
}

extern "C" void kernel_launch(void* const* d_in, const int* in_sizes, int n_in,
                              void* d_out, int out_size, void* d_ws, size_t ws_size,
                              hipStream_t stream) {
  const float* x   = (const float*)d_in[0];
  const float* w1  = (const float*)d_in[2];
  const float* g1  = (const float*)d_in[3];
  const float* b1  = (const float*)d_in[4];
  const float* w2  = (const float*)d_in[5];
  const float* g2  = (const float*)d_in[6];
  const float* b2  = (const float*)d_in[7];
  const float* w3  = (const float*)d_in[8];
  const float* g3  = (const float*)d_in[9];
  const float* b3  = (const float*)d_in[10];
  const float* w4  = (const float*)d_in[11];
  const float* g4  = (const float*)d_in[12];
  const float* b4  = (const float*)d_in[13];
  const float* w5  = (const float*)d_in[14];
  const float* g5  = (const float*)d_in[15];
  const float* b5  = (const float*)d_in[16];
  const float* l1w = (const float*)d_in[17];
  const float* l1b = (const float*)d_in[18];
  const float* g6  = (const float*)d_in[19];
  const float* b6  = (const float*)d_in[20];
  const float* l2w = (const float*)d_in[21];
  const float* l2b = (const float*)d_in[22];
  const float* g7  = (const float*)d_in[23];
  const float* b7  = (const float*)d_in[24];
  const float* l3w = (const float*)d_in[25];
  const float* l3b = (const float*)d_in[26];
  float* outp = (float*)d_out;

  char* ws = (char*)d_ws;
  int*      idx  = (int*)(ws + 0);
  ushort_t* x1   = (ushort_t*)(ws + 2621440);
  ushort_t* x2   = (ushort_t*)(ws + 11010048);
  ushort_t* x3   = (ushort_t*)(ws + 27787264);
  ushort_t* w2p  = (ushort_t*)(ws + 61341696);  // overlays x4p (disjoint live ranges)
  float*    x4p  = (float*)(ws + 61341696);
  ushort_t* xgp  = (ushort_t*)(ws + 61407232);
  ushort_t* w3fp = (ushort_t*)(ws + 61440000);
  ushort_t* w4p  = (ushort_t*)(ws + 61472768);
  ushort_t* l2wp = (ushort_t*)(ws + 61603840);
  ushort_t* l1wp = (ushort_t*)(ws + 62128128);
  ushort_t* h5   = (ushort_t*)(ws + 65142784);
  float*    h6   = (float*)(ws + 11010048);  // overlays x2/x3 (dead after l1 gemm)

  knn_kernel<<<NPID / 4, 256, 0, stream>>>(x, idx);
  prep_kernel<<<3632, 256, 0, stream>>>(w3, w4, l1w, l2w, w2, w3fp, w4p, l1wp, l2wp, w2p);
  edge_kernel<<<NPID / 64, 256, 0, stream>>>(x, idx, w1, g1, b1, w2p, g2, b2, x1);
  // x2 = lrelu(bn(x1 @ w3f^T))      M=32768 K=64  O=128
  gemm_bf16<0, 0><<<256, 256, 0, stream>>>(x1, w3fp, x2, 64, 128, 1, X1_PO, 8192, X2_PO,
                                           g3, b3, nullptr, 1, nullptr, nullptr, nullptr, nullptr);
  // x3 = lrelu(bn(x2 @ w4^T))       K=128 O=256
  gemm_bf16<0, 0><<<512, 256, 0, stream>>>(x2, w4p, x3, 128, 256, 2, X2_PO, 32768, X3_PO,
                                           g4, b4, nullptr, 1, nullptr, nullptr, nullptr, nullptr);
  max_kernel<<<256, 256, 0, stream>>>(x3, x4p);
  xg_kernel<<<8, 256, 0, stream>>>(x4p, w5, g5, b5, xgp);
  // h5 = lrelu(bn(feat @ l1w^T + l1b))  K=1472 O=512  (concat gather)
  gemm_bf16<1, 0><<<1024, 256, 0, stream>>>(nullptr, l1wp, h5, 1472, 512, 4, 0, 753664, 16777216,
                                            g6, b6, l1b, 1, xgp, x3, x2, x1);
  // h6 = lrelu(bn(h5 @ l2w^T + l2b))    K=512 O=256  -> f32
  gemm_bf16<0, 1><<<512, 256, 0, stream>>>(h5, l2wp, h6, 512, 256, 2, 16777216, 131072, 0,
                                           g7, b7, l2b, 1, nullptr, nullptr, nullptr, nullptr);
  l3_kernel<<<128, 256, 0, stream>>>(h6, l3w, l3b, outp);
}

// Round 7
// 271.670 us; speedup vs baseline: 7.7991x; 2.1063x over previous
//
#include <hip/hip_runtime.h>

// ColorGradientNet on MI355X — round 7:
//  * ALGEBRAIC: xg part of feat (K=1024 of 1472) is n-invariant -> precompute
//    yb[b] = l1w[:, :1024] @ xg[b] once, fold into l1 epilogue bias. l1 GEMM K: 1472->448.
//  * xg path parallelized: x4 seg-max (8 blk) -> xg 1-wave/output (2048 blk)
//    -> yb 1-wave/output (1024 blk). All f32 (more exact than before).
//  * prep compacts l1w tail columns (512 x 448) so B staging stride = Ktot.
// knn / edge / GEMM structure unchanged from round 6.
// Workspace layout (bytes):
//   idx  @ 0          : 32768*20 int32                  = 2,621,440
//   x1   @ 2621440    : 2 planes x 2,097,152 ushort     = 8,388,608
//   x2   @ 11010048   : 2 x 4,194,304 ushort            = 16,777,216
//   x3   @ 27787264   : 2 x 8,388,608 ushort            = 33,554,432
//   w2p  @ 61341696   : 2 x 4,096 ushort (overlays x4p; live [prep,edge])
//   x4p  @ 61341696   : 8*8*256 f32 (65,536; live [max,x4])
//   xgf  @ 61407232   : 8*1024 f32 (32,768; live [xg,yb])
//   x4f  @ 61440000   : 8*256 f32 (8,192; overlays w3fp tail-life; live [x4,xg])
//   yb   @ 61448192   : 8*512 f32 (16,384; live [yb,l1 gemm])
//   w3f  @ 61440000   : 2 x 8,192 ushort (live [prep, x2 gemm] — dead before x4f/yb)
//   w4p  @ 61472768   : 2 x 32,768 ushort
//   l2wp @ 61603840   : 2 x 131,072 ushort
//   l1wp @ 62128128   : 2 x 229,376 ushort (l1w tail cols 1024..1471)
//   h5   @ 65142784   : 2 x 16,777,216 ushort           (end 132,251,648)
//   h6   @ 11010048   : 32768*256 f32 (overlays x2/x3 — dead after l1 gemm)

#define KNN 20
#define NPID 32768
#define RS 0.99999500003750f  // 1/sqrt(1+1e-5)

#define X3_PO 8388608
#define X2_PO 4194304
#define X1_PO 2097152

typedef unsigned short ushort_t;
typedef unsigned int u32;
typedef __attribute__((ext_vector_type(8))) short bf16x8;
typedef __attribute__((ext_vector_type(4))) float f32x4;

#define LDS_PTR(p) ((__attribute__((address_space(3))) void*)(p))
#define GLB_PTR(p) ((const __attribute__((address_space(1))) void*)(p))

__device__ __forceinline__ float lrelu(float z) { return z >= 0.f ? z : 0.2f * z; }
__device__ __forceinline__ unsigned short f2bf(float f) {
  unsigned int u = __float_as_uint(f);
  return (unsigned short)((u + 0x7fffu + ((u >> 16) & 1u)) >> 16);
}
__device__ __forceinline__ float bf2f(unsigned short h) { return __uint_as_float((unsigned int)h << 16); }
__device__ __forceinline__ u32 pack2(u32 e0, u32 e1) { return (e1 << 16) | (e0 & 0xffffu); }
__device__ __forceinline__ f32x4 mfma16(uint4 a, uint4 b, f32x4 c) {
  return __builtin_amdgcn_mfma_f32_16x16x32_bf16(
      __builtin_bit_cast(bf16x8, a), __builtin_bit_cast(bf16x8, b), c, 0, 0, 0);
}

// ---------------- kNN: LDS-staged distances + threshold + bitonic ----------------
__global__ __launch_bounds__(256) void knn_kernel(const float* __restrict__ x, int* __restrict__ idxo) {
  __shared__ __align__(16) float pl[3][2048];
  __shared__ float cval[4][64];
  __shared__ int cidx[4][64];
  const int tid = threadIdx.x, lane = tid & 63, wave = tid >> 6;
  const int pid = blockIdx.x * 4 + wave;
  const int b = pid >> 12, n = pid & 4095;
  const float* xb = x + (size_t)b * 40960;
  const float px = xb[n], py = xb[4096 + n], pz = xb[8192 + n];
  const float xxn = __fadd_rn(__fadd_rn(__fmul_rn(px, px), __fmul_rn(py, py)), __fmul_rn(pz, pz));
  float d[64];
  float lmax = -3.4e38f;
#pragma unroll
  for (int t = 0; t < 2; ++t) {
    if (t) __syncthreads();
#pragma unroll
    for (int r = 0; r < 6; ++r) {
      const int q = (r * 4 + wave) * 64 + lane;
      const int p = q >> 9, f = q & 511;
      const float* src = xb + p * 4096 + t * 2048 + f * 4;
      __builtin_amdgcn_global_load_lds(GLB_PTR(src), LDS_PTR((char*)pl + (r * 4 + wave) * 1024), 16, 0, 0);
    }
    __syncthreads();
#pragma unroll
    for (int j = 0; j < 32; ++j) {
      const int ml = j * 64 + lane;
      const float qx = pl[0][ml], qy = pl[1][ml], qz = pl[2][ml];
      const float xxm = __fadd_rn(__fadd_rn(__fmul_rn(qx, qx), __fmul_rn(qy, qy)), __fmul_rn(qz, qz));
      const float inner = __fadd_rn(__fadd_rn(__fmul_rn(px, qx), __fmul_rn(py, qy)), __fmul_rn(pz, qz));
      const float pd = __fsub_rn(__fsub_rn(__fmul_rn(2.0f, inner), xxn), xxm);
      d[t * 32 + j] = pd;
      lmax = fmaxf(lmax, pd);
    }
  }
  float v = lmax;
#pragma unroll
  for (int k = 2; k <= 64; k <<= 1) {
#pragma unroll
    for (int j = k >> 1; j > 0; j >>= 1) {
      const float ov = __shfl_xor(v, j, 64);
      const bool keepMax = (((lane & k) == 0) == ((lane & j) == 0));
      v = keepMax ? fmaxf(v, ov) : fminf(v, ov);
    }
  }
  const float t0 = __shfl(v, 19, 64);
  int base = 0;
#pragma unroll
  for (int j = 0; j < 64; ++j) {
    const bool take = (d[j] >= t0);
    const unsigned long long mk = __ballot(take);
    if (take) {
      const int pos = base + __popcll(mk & ((1ull << lane) - 1ull));
      if (pos < 64) {
        cval[wave][pos] = d[j];
        cidx[wave][pos] = ((j >> 5) << 11) + ((j & 31) << 6) + lane;
      }
    }
    base += (int)__popcll(mk);
  }
  const int C = base;
  int* out = idxo + (size_t)pid * KNN;
  if (C <= 64) {
    unsigned long long key = 0ull;
    if (lane < C) {
      const unsigned int u = __float_as_uint(cval[wave][lane]);
      const unsigned int ou = (u & 0x80000000u) ? ~u : (u | 0x80000000u);
      key = ((unsigned long long)ou << 32) | (unsigned long long)(0xFFFFFFFFu - (unsigned int)cidx[wave][lane]);
    }
#pragma unroll
    for (int k = 2; k <= 64; k <<= 1) {
#pragma unroll
      for (int j = k >> 1; j > 0; j >>= 1) {
        const unsigned long long ok = (unsigned long long)__shfl_xor((long long)key, j, 64);
        const bool keepMax = (((lane & k) == 0) == ((lane & j) == 0));
        const bool gt = key > ok;
        key = (keepMax == gt) ? key : ok;
      }
    }
    if (lane < KNN) out[lane] = (int)(0xFFFFFFFFu - (unsigned int)key);
  } else {
    unsigned long long used = 0ull;
#pragma unroll 1
    for (int it = 0; it < KNN; ++it) {
      float lv = -3.4e38f;
      int li = 1 << 30;
#pragma unroll
      for (int j = 0; j < 64; ++j) {
        if (!((used >> j) & 1ull) && d[j] > lv) {
          lv = d[j];
          li = ((j >> 5) << 11) + ((j & 31) << 6) + lane;
        }
      }
      float bv = lv;
      int bi = li;
#pragma unroll
      for (int s = 1; s < 64; s <<= 1) {
        const float ovv = __shfl_xor(bv, s, 64);
        const int oii = __shfl_xor(bi, s, 64);
        if (ovv > bv || (ovv == bv && oii < bi)) { bv = ovv; bi = oii; }
      }
      if (lane == 0) out[it] = bi;
      if ((bi & 63) == lane) {
        const int jg = ((bi >> 11) << 5) + ((bi & 2047) >> 6);
        used |= 1ull << jg;
      }
    }
  }
}

// ---------------- edge: fused MFMA h1(9->64) + h2(64->64) + max over k ----------------
__global__ __launch_bounds__(256) void edge_kernel(const float* __restrict__ x, const int* __restrict__ idxi,
    const float* __restrict__ w1, const float* __restrict__ g1, const float* __restrict__ b1,
    const ushort_t* __restrict__ w2p, const float* __restrict__ g2, const float* __restrict__ b2,
    ushort_t* __restrict__ x1o) {
  __shared__ u32 hstage[4][16][64];
  const int tid = threadIdx.x, lane = tid & 63, wave = tid >> 6;
  const int fr = lane & 15, kg = lane >> 4;
  const int pbase = blockIdx.x * 64 + wave * 16;
  const int b = (blockIdx.x * 64) >> 12;
  const float* xq = x + (size_t)b * 40960;

  const int nA = (pbase + fr) & 4095;
  float cv[6]; ushort_t chv[6], clv[6];
#pragma unroll
  for (int j = 0; j < 6; ++j) {
    cv[j] = xq[j * 4096 + nA];
    chv[j] = f2bf(cv[j]);
    clv[j] = f2bf(cv[j] - bf2f(chv[j]));
  }
  const float crv = cv[3], cgv = cv[4], cbv = cv[5];

  u32 aC0 = 0, aC1 = 0, aC2 = 0, aC3 = 0;
  if (kg == 0) { aC0 = pack2(chv[0], chv[1]); aC1 = pack2(chv[2], chv[3]); aC2 = pack2(chv[4], chv[5]); }
  else if (kg == 1) { aC0 = (u32)chv[0] << 16; aC1 = pack2(chv[1], chv[2]); aC2 = pack2(chv[3], chv[4]); aC3 = chv[5]; }
  else if (kg == 2) { aC1 = pack2(clv[0], clv[1]); aC2 = pack2(clv[2], clv[3]); aC3 = pack2(clv[4], clv[5]); }

  float s1v[4], t1v[4], s2v[4], t2v[4];
#pragma unroll
  for (int fj = 0; fj < 4; ++fj) {
    const int och = fj * 16 + fr;
    s1v[fj] = g1[och] * RS; t1v[fj] = b1[och];
    s2v[fj] = g2[och] * RS; t2v[fj] = b2[och];
  }

  uint4 w1Bv[4];
#pragma unroll
  for (int fj = 0; fj < 4; ++fj) {
    const int och = fj * 16 + fr;
    ushort_t wh[9], wl[9];
#pragma unroll
    for (int j = 0; j < 9; ++j) {
      const float wv = w1[och * 9 + j];
      wh[j] = f2bf(wv);
      wl[j] = f2bf(wv - bf2f(wh[j]));
    }
    uint4 q;
    if (kg == 0)      { q.x = pack2(wh[0], wh[1]); q.y = pack2(wh[2], wh[3]); q.z = pack2(wh[4], wh[5]); q.w = pack2(wh[6], wh[7]); }
    else if (kg == 1) { q.x = pack2(wh[8], wl[0]); q.y = pack2(wl[1], wl[2]); q.z = pack2(wl[3], wl[4]); q.w = pack2(wl[5], wl[6]); }
    else if (kg == 2) { q.x = pack2(wl[7], wl[8]); q.y = pack2(wh[0], wh[1]); q.z = pack2(wh[2], wh[3]); q.w = pack2(wh[4], wh[5]); }
    else              { q.x = pack2(wh[6], wh[7]); q.y = pack2(wh[8], 0);     q.z = 0;                   q.w = 0; }
    w1Bv[fj] = q;
  }

  uint4 w2Bh[4][2], w2Bl[4][2];
#pragma unroll
  for (int fj = 0; fj < 4; ++fj) {
    const int och = fj * 16 + fr;
#pragma unroll
    for (int sub = 0; sub < 2; ++sub) {
      const ushort_t* ph = w2p + och * 64 + sub * 32 + kg * 8;
      w2Bh[fj][sub] = *(const uint4*)ph;
      w2Bl[fj][sub] = *(const uint4*)(ph + 4096);
    }
  }

  const int prow = (pbase + fr) * KNN;
  int miA = idxi[prow];
  int miN = idxi[prow + 1];
  float pr = xq[12288 + miA], pg = xq[16384 + miA], pb = xq[20480 + miA];

  f32x4 xm[4];
#pragma unroll
  for (int fj = 0; fj < 4; ++fj) { xm[fj][0] = -3.4e38f; xm[fj][1] = -3.4e38f; xm[fj][2] = -3.4e38f; xm[fj][3] = -3.4e38f; }
  const f32x4 zz = {0.f, 0.f, 0.f, 0.f};

#pragma unroll 1
  for (int kk = 0; kk < KNN; ++kk) {
    const float nrv = pr, ngv = pg, nbv = pb;
    if (kk < KNN - 1) { pr = xq[12288 + miN]; pg = xq[16384 + miN]; pb = xq[20480 + miN]; }
    if (kk < KNN - 2) { miN = idxi[prow + kk + 2]; }

    const float dr = crv - nrv, dg = cgv - ngv, db = cbv - nbv;
    const ushort_t drh = f2bf(dr), dgh = f2bf(dg), dbh = f2bf(db);
    const ushort_t drl = f2bf(dr - bf2f(drh)), dgl = f2bf(dg - bf2f(dgh)), dbl = f2bf(db - bf2f(dbh));

    uint4 aF;
    if (kg == 0)      { aF.x = aC0; aF.y = aC1; aF.z = aC2; aF.w = pack2(drh, dgh); }
    else if (kg == 1) { aF.x = aC0 | dbh; aF.y = aC1; aF.z = aC2; aF.w = aC3 | ((u32)drh << 16); }
    else if (kg == 2) { aF.x = pack2(dgh, dbh); aF.y = aC1; aF.z = aC2; aF.w = aC3; }
    else              { aF.x = pack2(drl, dgl); aF.y = (u32)dbl; aF.z = 0; aF.w = 0; }

    f32x4 h1a[4];
#pragma unroll
    for (int fj = 0; fj < 4; ++fj) h1a[fj] = mfma16(aF, w1Bv[fj], zz);

#pragma unroll
    for (int fj = 0; fj < 4; ++fj)
#pragma unroll
      for (int r = 0; r < 4; ++r) {
        float z = h1a[fj][r] * s1v[fj] + t1v[fj];
        z = fmaxf(z, 0.2f * z);
        const ushort_t hi = f2bf(z), lo = f2bf(z - bf2f(hi));
        const int pC = kg * 4 + r;
        hstage[wave][pC][(fj * 16 + fr) ^ ((pC & 7) << 3)] = ((u32)hi << 16) | lo;
      }

    f32x4 a2[4] = {zz, zz, zz, zz};
#pragma unroll
    for (int sub = 0; sub < 2; ++sub) {
      const u32* rp = &hstage[wave][fr][(sub * 32 + kg * 8) ^ ((fr & 7) << 3)];
      const uint4 q0 = *(const uint4*)rp;
      const uint4 q1 = *(const uint4*)(rp + 4);
      uint4 ah, al;
      ah.x = __builtin_amdgcn_perm(q0.y, q0.x, 0x07060302u); al.x = __builtin_amdgcn_perm(q0.y, q0.x, 0x05040100u);
      ah.y = __builtin_amdgcn_perm(q0.w, q0.z, 0x07060302u); al.y = __builtin_amdgcn_perm(q0.w, q0.z, 0x05040100u);
      ah.z = __builtin_amdgcn_perm(q1.y, q1.x, 0x07060302u); al.z = __builtin_amdgcn_perm(q1.y, q1.x, 0x05040100u);
      ah.w = __builtin_amdgcn_perm(q1.w, q1.z, 0x07060302u); al.w = __builtin_amdgcn_perm(q1.w, q1.z, 0x05040100u);
#pragma unroll
      for (int fj = 0; fj < 4; ++fj) {
        a2[fj] = mfma16(ah, w2Bh[fj][sub], a2[fj]);
        a2[fj] = mfma16(ah, w2Bl[fj][sub], a2[fj]);
        a2[fj] = mfma16(al, w2Bh[fj][sub], a2[fj]);
      }
    }

#pragma unroll
    for (int fj = 0; fj < 4; ++fj)
#pragma unroll
      for (int r = 0; r < 4; ++r) {
        float z = a2[fj][r] * s2v[fj] + t2v[fj];
        z = fmaxf(z, 0.2f * z);
        xm[fj][r] = fmaxf(xm[fj][r], z);
      }
  }

#pragma unroll
  for (int fj = 0; fj < 4; ++fj)
#pragma unroll
    for (int r = 0; r < 4; ++r) {
      const size_t e = (size_t)(pbase + kg * 4 + r) * 64 + fj * 16 + fr;
      const float v = xm[fj][r];
      const ushort_t hi = f2bf(v);
      x1o[e] = hi;
      x1o[X1_PO + e] = f2bf(v - bf2f(hi));
    }
}

// ---------------- weight prep: fold w3 + split weights (l1w: tail cols only) ----------------
__global__ __launch_bounds__(256) void prep_kernel(const float* __restrict__ w3, const float* __restrict__ w4,
    const float* __restrict__ l1w, const float* __restrict__ l2w, const float* __restrict__ w2,
    ushort_t* __restrict__ w3fp, ushort_t* __restrict__ w4p,
    ushort_t* __restrict__ l1wp, ushort_t* __restrict__ l2wp, ushort_t* __restrict__ w2p) {
  const int i = blockIdx.x * 256 + threadIdx.x;  // 0 .. 405503
  float f; ushort_t* hp; int n, j;
  if (i < 8192) {
    const int o = i >> 6, c = i & 63;
    f = w3[o * 128 + c] + w3[o * 128 + 64 + c];
    hp = w3fp; n = 8192; j = i;
  } else if (i < 8192 + 32768) {
    j = i - 8192; f = w4[j]; hp = w4p; n = 32768;
  } else if (i < 8192 + 32768 + 131072) {
    j = i - 8192 - 32768; f = l2w[j]; hp = l2wp; n = 131072;
  } else if (i < 172032 + 229376) {
    j = i - 172032;                       // 512 x 448 tail block of l1w
    const int row = j / 448, col = j - row * 448;
    f = l1w[row * 1472 + 1024 + col];
    hp = l1wp; n = 229376;
  } else if (i < 401408 + 4096) {
    j = i - 401408; f = w2[j]; hp = w2p; n = 4096;
  } else return;
  const unsigned short h = f2bf(f);
  hp[j] = h;
  hp[n + j] = f2bf(f - bf2f(h));
}

// ---------------- split-bf16 MFMA GEMM ----------------
// MODE 1: gather concat [x3(256)|x2(128)|x1(64)], Ktot=448; epilogue adds per-batch yb.
template <int MODE, int OUTF32>
__global__ __launch_bounds__(256) void gemm_bf16(
    const ushort_t* __restrict__ A, const ushort_t* __restrict__ W, void* __restrict__ outv,
    const int Ktot, const int Nout, const int n_tiles,
    const int aPO, const int wPO, const int outPO,
    const float* __restrict__ gg, const float* __restrict__ bb,
    const float* __restrict__ linb, const int do_lrelu,
    const float* __restrict__ ybp, const ushort_t* __restrict__ x3,
    const ushort_t* __restrict__ x2, const ushort_t* __restrict__ x1) {
  __shared__ __align__(16) ushort_t lds[32768];
  const int tid = threadIdx.x, lane = tid & 63, wid = tid >> 6;
  const int nwg = gridDim.x;
  int id = (blockIdx.x & 7) * (nwg >> 3) + (blockIdx.x >> 3);
  const int mt = id / n_tiles, nt = id - mt * n_tiles;
  const int m0 = mt * 128, o0 = nt * 128;
  const int fr = lane & 15, kg = lane >> 4;
  const int wr = wid >> 1, wc = wid & 1;
  const int srow = lane >> 3, sslot = lane & 7;
  int rA[4], rB[4];
#pragma unroll
  for (int i = 0; i < 4; ++i) { rA[i] = wr * 64 + i * 16 + fr; rB[i] = wc * 64 + i * 16 + fr; }
  f32x4 acc[4][4] = {};
  const ushort_t* srcB = (wid == 2) ? W : W + wPO;
  const ushort_t* srcA0 = (MODE == 0) ? ((wid == 0) ? A : A + aPO) : nullptr;
  const int pl = (wid == 1);

  for (int kc = 0; kc < Ktot; kc += 64) {
#pragma unroll
    for (int c = 0; c < 16; ++c) {
      const int row = c * 8 + srow;
      const int rslot = sslot ^ (row & 7);
      const int k = kc + rslot * 8;
      const ushort_t* q;
      if (wid >= 2) {
        q = srcB + (size_t)(o0 + row) * Ktot + k;
      } else if (MODE == 0) {
        q = srcA0 + (size_t)(m0 + row) * Ktot + k;
      } else {
        const int m = m0 + row;
        if (k < 256)      q = x3 + pl * X3_PO + (size_t)m * 256 + k;
        else if (k < 384) q = x2 + pl * X2_PO + (size_t)m * 128 + (k - 256);
        else              q = x1 + pl * X1_PO + (size_t)m * 64 + (k - 384);
      }
      __builtin_amdgcn_global_load_lds(GLB_PTR(q), LDS_PTR(&lds[wid * 8192 + c * 512]), 16, 0, 0);
    }
    __syncthreads();
#pragma unroll
    for (int k0 = 0; k0 < 64; k0 += 32) {
      const int ks = (k0 >> 3) + kg;
      bf16x8 ah[4], al[4], bh[4], bl[4];
#pragma unroll
      for (int i = 0; i < 4; ++i) {
        const int off = rA[i] * 64 + ((ks ^ (rA[i] & 7)) << 3);
        ah[i] = *(const bf16x8*)&lds[off];
        al[i] = *(const bf16x8*)&lds[8192 + off];
      }
#pragma unroll
      for (int j = 0; j < 4; ++j) {
        const int off = rB[j] * 64 + ((ks ^ (rB[j] & 7)) << 3);
        bh[j] = *(const bf16x8*)&lds[16384 + off];
        bl[j] = *(const bf16x8*)&lds[24576 + off];
      }
#pragma unroll
      for (int i = 0; i < 4; ++i)
#pragma unroll
        for (int j = 0; j < 4; ++j) {
          acc[i][j] = __builtin_amdgcn_mfma_f32_16x16x32_bf16(ah[i], bh[j], acc[i][j], 0, 0, 0);
          acc[i][j] = __builtin_amdgcn_mfma_f32_16x16x32_bf16(ah[i], bl[j], acc[i][j], 0, 0, 0);
          acc[i][j] = __builtin_amdgcn_mfma_f32_16x16x32_bf16(al[i], bh[j], acc[i][j], 0, 0, 0);
        }
    }
    __syncthreads();
  }
  float s[4], t[4];
#pragma unroll
  for (int j = 0; j < 4; ++j) {
    const int o = o0 + wc * 64 + j * 16 + fr;
    s[j] = gg[o] * RS;
    float add = linb ? linb[o] : 0.f;
    if (MODE == 1) add += ybp[((m0 >> 12) << 9) + o];  // per-batch xg contribution
    t[j] = bb[o] + add * s[j];
  }
#pragma unroll
  for (int i = 0; i < 4; ++i) {
#pragma unroll
    for (int j = 0; j < 4; ++j) {
      const int col = o0 + wc * 64 + j * 16 + fr;
#pragma unroll
      for (int r = 0; r < 4; ++r) {
        const int row = m0 + wr * 64 + i * 16 + kg * 4 + r;
        float z = acc[i][j][r] * s[j] + t[j];
        if (do_lrelu) z = lrelu(z);
        if (OUTF32) {
          ((float*)outv)[(size_t)row * Nout + col] = z;
        } else {
          ushort_t* oh = (ushort_t*)outv;
          const unsigned short h = f2bf(z);
          oh[(size_t)row * Nout + col] = h;
          oh[outPO + (size_t)row * Nout + col] = f2bf(z - bf2f(h));
        }
      }
    }
  }
}

// ---------------- max over N (partial, 8 segments); x3 is bf16 hi/lo ----------------
__global__ __launch_bounds__(256) void max_kernel(const ushort_t* __restrict__ x3, float* __restrict__ x4p) {
  __shared__ float red[4][64];
  const int bid = blockIdx.x;
  const int q = bid & 3, seg = (bid >> 2) & 7, b = bid >> 5;
  const int cl = threadIdx.x & 63, nl = threadIdx.x >> 6;
  const int c = (q << 6) + cl;
  float acc = -3.4e38f;
  const int n0 = seg * 512;
  for (int n = n0 + nl; n < n0 + 512; n += 4) {
    const size_t e = ((size_t)b * 4096 + n) * 256 + c;
    acc = fmaxf(acc, bf2f(x3[e]) + bf2f(x3[X3_PO + e]));
  }
  red[nl][cl] = acc;
  __syncthreads();
  if (threadIdx.x < 64) {
    x4p[((size_t)b * 8 + seg) * 256 + c] = fmaxf(fmaxf(red[0][cl], red[1][cl]), fmaxf(red[2][cl], red[3][cl]));
  }
}

// ---------------- x4 = max over 8 segments (8 blocks) ----------------
__global__ __launch_bounds__(256) void x4_kernel(const float* __restrict__ x4p, float* __restrict__ x4f) {
  const int b = blockIdx.x, c = threadIdx.x;
  float v = x4p[(size_t)b * 2048 + c];
#pragma unroll
  for (int s = 1; s < 8; ++s) v = fmaxf(v, x4p[(size_t)b * 2048 + s * 256 + c]);
  x4f[b * 256 + c] = v;
}

// ---------------- xg = lrelu(bn(x4 @ w5^T)); one wave per output ----------------
__global__ __launch_bounds__(256) void xg_kernel(const float* __restrict__ x4f, const float* __restrict__ w5,
    const float* __restrict__ g5, const float* __restrict__ b5, float* __restrict__ xgf) {
  const int lane = threadIdx.x & 63, wave = threadIdx.x >> 6;
  const int o = blockIdx.x * 4 + wave;  // 0..8191 = b*1024 + oc
  const int b = o >> 10, oc = o & 1023;
  const float4 xv = *(const float4*)&x4f[b * 256 + lane * 4];
  const float4 w = *(const float4*)&w5[(size_t)oc * 256 + lane * 4];
  float acc = xv.x * w.x + xv.y * w.y + xv.z * w.z + xv.w * w.w;
#pragma unroll
  for (int s = 1; s < 64; s <<= 1) acc += __shfl_xor(acc, s, 64);
  if (lane == 0) xgf[o] = lrelu(acc * (g5[oc] * RS) + b5[oc]);
}

// ---------------- yb[b][o] = l1w[o, :1024] . xg[b]  (f32); one wave per output ----------------
__global__ __launch_bounds__(256) void yb_kernel(const float* __restrict__ xgf, const float* __restrict__ l1w,
    float* __restrict__ yb) {
  const int lane = threadIdx.x & 63, wave = threadIdx.x >> 6;
  const int o = blockIdx.x * 4 + wave;  // 0..4095 = b*512 + oc
  const int b = o >> 9, oc = o & 511;
  float acc = 0.f;
#pragma unroll
  for (int i = 0; i < 4; ++i) {
    const int k = i * 256 + lane * 4;
    const float4 w = *(const float4*)&l1w[(size_t)oc * 1472 + k];
    const float4 g = *(const float4*)&xgf[b * 1024 + k];
    acc += w.x * g.x + w.y * g.y + w.z * g.z + w.w * g.w;
  }
#pragma unroll
  for (int s = 1; s < 64; s <<= 1) acc += __shfl_xor(acc, s, 64);
  if (lane == 0) yb[o] = acc;
}

// ---------------- final 256->2 + transpose to (B,2,N) ----------------
__global__ __launch_bounds__(256) void l3_kernel(const float* __restrict__ h6, const float* __restrict__ l3w,
    const float* __restrict__ l3b, float* __restrict__ out) {
  __shared__ float wl[512];
  const int tid = threadIdx.x;
  wl[tid] = l3w[tid]; wl[256 + tid] = l3w[256 + tid];
  __syncthreads();
  const int m = blockIdx.x * 256 + tid;
  float a0 = 0.f, a1 = 0.f;
#pragma unroll
  for (int c = 0; c < 256; c += 4) {
    const float4 h = *(const float4*)(h6 + (size_t)m * 256 + c);
    a0 += h.x * wl[c] + h.y * wl[c + 1] + h.z * wl[c + 2] + h.w * wl[c + 3];
    a1 += h.x * wl[256 + c] + h.y * wl[256 + c + 1] + h.z * wl[256 + c + 2] + h.w * wl[256 + c + 3];
  }
  const int b = m >> 12, n = m & 4095;
  out[(size_t)b * 8192 + n] = a0 + l3b[0];
  out[(size_t)b * 8192 + 4096 + n] = a1 + l3b[1];
}

extern "C" void kernel_launch(void* const* d_in, const int* in_sizes, int n_in,
                              void* d_out, int out_size, void* d_ws, size_t ws_size,
                              hipStream_t stream) {
  const float* x   = (const float*)d_in[0];
  const float* w1  = (const float*)d_in[2];
  const float* g1  = (const float*)d_in[3];
  const float* b1  = (const float*)d_in[4];
  const float* w2  = (const float*)d_in[5];
  const float* g2  = (const float*)d_in[6];
  const float* b2  = (const float*)d_in[7];
  const float* w3  = (const float*)d_in[8];
  const float* g3  = (const float*)d_in[9];
  const float* b3  = (const float*)d_in[10];
  const float* w4  = (const float*)d_in[11];
  const float* g4  = (const float*)d_in[12];
  const float* b4  = (const float*)d_in[13];
  const float* w5  = (const float*)d_in[14];
  const float* g5  = (const float*)d_in[15];
  const float* b5  = (const float*)d_in[16];
  const float* l1w = (const float*)d_in[17];
  const float* l1b = (const float*)d_in[18];
  const float* g6  = (const float*)d_in[19];
  const float* b6  = (const float*)d_in[20];
  const float* l2w = (const float*)d_in[21];
  const float* l2b = (const float*)d_in[22];
  const float* g7  = (const float*)d_in[23];
  const float* b7  = (const float*)d_in[24];
  const float* l3w = (const float*)d_in[25];
  const float* l3b = (const float*)d_in[26];
  float* outp = (float*)d_out;

  char* ws = (char*)d_ws;
  int*      idx  = (int*)(ws + 0);
  ushort_t* x1   = (ushort_t*)(ws + 2621440);
  ushort_t* x2   = (ushort_t*)(ws + 11010048);
  ushort_t* x3   = (ushort_t*)(ws + 27787264);
  ushort_t* w2p  = (ushort_t*)(ws + 61341696);  // overlays x4p (disjoint live ranges)
  float*    x4p  = (float*)(ws + 61341696);
  float*    xgf  = (float*)(ws + 61407232);
  float*    x4f  = (float*)(ws + 61440000);     // overlays w3fp (dead after x2 gemm)
  float*    ybp  = (float*)(ws + 61448192);     // overlays w3fp tail (dead after x2 gemm)
  ushort_t* w3fp = (ushort_t*)(ws + 61440000);
  ushort_t* w4p  = (ushort_t*)(ws + 61472768);
  ushort_t* l2wp = (ushort_t*)(ws + 61603840);
  ushort_t* l1wp = (ushort_t*)(ws + 62128128);
  ushort_t* h5   = (ushort_t*)(ws + 65142784);
  float*    h6   = (float*)(ws + 11010048);     // overlays x2/x3 (dead after l1 gemm)

  knn_kernel<<<NPID / 4, 256, 0, stream>>>(x, idx);
  prep_kernel<<<1584, 256, 0, stream>>>(w3, w4, l1w, l2w, w2, w3fp, w4p, l1wp, l2wp, w2p);
  edge_kernel<<<NPID / 64, 256, 0, stream>>>(x, idx, w1, g1, b1, w2p, g2, b2, x1);
  // x2 = lrelu(bn(x1 @ w3f^T))      M=32768 K=64  O=128
  gemm_bf16<0, 0><<<256, 256, 0, stream>>>(x1, w3fp, x2, 64, 128, 1, X1_PO, 8192, X2_PO,
                                           g3, b3, nullptr, 1, nullptr, nullptr, nullptr, nullptr);
  // x3 = lrelu(bn(x2 @ w4^T))       K=128 O=256
  gemm_bf16<0, 0><<<512, 256, 0, stream>>>(x2, w4p, x3, 128, 256, 2, X2_PO, 32768, X3_PO,
                                           g4, b4, nullptr, 1, nullptr, nullptr, nullptr, nullptr);
  max_kernel<<<256, 256, 0, stream>>>(x3, x4p);
  x4_kernel<<<8, 256, 0, stream>>>(x4p, x4f);
  xg_kernel<<<2048, 256, 0, stream>>>(x4f, w5, g5, b5, xgf);
  yb_kernel<<<1024, 256, 0, stream>>>(xgf, l1w, ybp);
  // h5 = lrelu(bn(feat @ l1w^T + l1b))  K=448 (x3|x2|x1) + yb folded into bias
  gemm_bf16<1, 0><<<1024, 256, 0, stream>>>(nullptr, l1wp, h5, 448, 512, 4, 0, 229376, 16777216,
                                            g6, b6, l1b, 1, ybp, x3, x2, x1);
  // h6 = lrelu(bn(h5 @ l2w^T + l2b))    K=512 O=256  -> f32
  gemm_bf16<0, 1><<<512, 256, 0, stream>>>(h5, l2wp, h6, 512, 256, 2, 16777216, 131072, 0,
                                           g7, b7, l2b, 1, nullptr, nullptr, nullptr, nullptr);
  l3_kernel<<<128, 256, 0, stream>>>(h6, l3w, l3b, outp);
}